// Round 1
// baseline (892.895 us; speedup 1.0000x reference)
//
#include <hip/hip_runtime.h>
#include <math.h>

// MMGCN fused pipeline for MI355X (gfx950).
// Output [N,384]: cols 0:128 = leaky(x_norm) (shared by both branches),
// cols 128:256 = 0.5*(leaky(xhat_v)+leaky(xhat_t)), cols 256:384 = 0.5*(xhat2_v+xhat2_t).

__device__ __forceinline__ float lrelu(float v) { return v >= 0.0f ? v : 0.01f * v; }

// ---------------- degree histograms ----------------
__global__ void k_degrees(const int* __restrict__ src, const int* __restrict__ dst,
                          int* __restrict__ deg_out, int* __restrict__ deg_in, int E) {
    int e = blockIdx.x * blockDim.x + threadIdx.x;
    if (e < E) {
        atomicAdd(&deg_out[src[e]], 1);
        atomicAdd(&deg_in[dst[e]], 1);
    }
}

// ---------------- norms: clip(deg,1)^-0.5 ----------------
__global__ void k_norms(const int* __restrict__ deg_out, const int* __restrict__ deg_in,
                        float* __restrict__ onrm, float* __restrict__ inrm, int n) {
    int i = blockIdx.x * blockDim.x + threadIdx.x;
    if (i < n) {
        onrm[i] = 1.0f / sqrtf((float)max(deg_out[i], 1));
        inrm[i] = 1.0f / sqrtf((float)max(deg_in[i], 1));
    }
}

// ---------------- single-block prefix scan (deg_in -> row_ptr) ----------------
__global__ void k_scan(const int* __restrict__ deg, int* __restrict__ row_ptr, int n) {
    __shared__ int wsum[16];
    __shared__ int wpre[16];
    int lane = threadIdx.x & 63;
    int wid  = threadIdx.x >> 6;
    int carry = 0;
    if (threadIdx.x == 0) row_ptr[0] = 0;
    for (int base = 0; base < n; base += 1024) {
        int i = base + (int)threadIdx.x;
        int v = (i < n) ? deg[i] : 0;
        int s = v;
        #pragma unroll
        for (int off = 1; off < 64; off <<= 1) {
            int t = __shfl_up(s, off, 64);
            if (lane >= off) s += t;
        }
        if (lane == 63) wsum[wid] = s;
        __syncthreads();
        if (wid == 0) {
            int wv = (lane < 16) ? wsum[lane] : 0;
            int ss = wv;
            #pragma unroll
            for (int off = 1; off < 16; off <<= 1) {
                int t = __shfl_up(ss, off, 64);
                if (lane >= off) ss += t;
            }
            if (lane < 16) wpre[lane] = ss - wv;   // exclusive prefix of wave sums
        }
        __syncthreads();
        int incl = s + wpre[wid];
        if (i < n) row_ptr[i + 1] = carry + incl;
        carry += wpre[15] + wsum[15];
        __syncthreads();   // protect wsum/wpre before next chunk
    }
}

// ---------------- CSR fill (order within a row is irrelevant for the sum) ----------------
__global__ void k_fill(const int* __restrict__ src, const int* __restrict__ dst,
                       const int* __restrict__ row_ptr, int* __restrict__ cursor,
                       int* __restrict__ col, int E) {
    int e = blockIdx.x * blockDim.x + threadIdx.x;
    if (e < E) {
        int d = dst[e];
        int pos = atomicAdd(&cursor[d], 1);
        col[row_ptr[d] + pos] = src[e];
    }
}

// ---------------- row L2-normalize x; out[:,0:128] = leaky(xn) ----------------
__global__ void k_normx(const float* __restrict__ x, float* __restrict__ xn,
                        float* __restrict__ out, int n) {
    int gtid = blockIdx.x * blockDim.x + threadIdx.x;
    int row  = gtid >> 6;
    int lane = gtid & 63;
    if (row >= n) return;
    int c = lane * 2;
    float2 v = *(const float2*)&x[(size_t)row * 128 + c];
    float s = v.x * v.x + v.y * v.y;
    #pragma unroll
    for (int off = 1; off < 64; off <<= 1) s += __shfl_xor(s, off, 64);
    float scale = 1.0f / fmaxf(sqrtf(s), 1e-12f);
    float nx = v.x * scale, ny = v.y * scale;
    *(float2*)&xn[(size_t)row * 128 + c] = make_float2(nx, ny);
    *(float2*)&out[(size_t)row * 384 + c] = make_float2(lrelu(nx), lrelu(ny));
}

// ---------------- tiled f32 GEMM: Y = f(A)*rowscale @ W ----------------
// A operand: rows of A0 (k<128) and optionally A1 (k>=128, K=256), with
// optional leaky applied before the out_norm row scaling (fused GraphConv input).
template<int K, bool LEAKY>
__global__ __launch_bounds__(256) void k_gemm(const float* __restrict__ A0,
                                              const float* __restrict__ A1,
                                              const float* __restrict__ W,
                                              const float* __restrict__ rowscale,
                                              float* __restrict__ Y, int n) {
    __shared__ float As[32][68];    // [k][row], padded: row stride 272B (16B-aligned, bank-spread)
    __shared__ float Bs[32][128];   // [k][col]
    int tid = threadIdx.x;
    int tr = tid >> 4;              // 0..15 -> rows tr*4..+3
    int tc = tid & 15;              // 0..15 -> cols tc*8..+7
    int row0 = blockIdx.x * 64;

    float acc[4][8];
    #pragma unroll
    for (int r = 0; r < 4; r++)
        #pragma unroll
        for (int c = 0; c < 8; c++) acc[r][c] = 0.0f;

    for (int k0 = 0; k0 < K; k0 += 32) {
        const float* srcp = A0;
        int kb = k0;
        if (K > 128 && k0 >= 128) { srcp = A1; kb = k0 - 128; }
        // A tile: 64 rows x 32 k  (512 float4, 2 per thread), stored transposed
        #pragma unroll
        for (int half = 0; half < 2; half++) {
            int f  = tid + half * 256;
            int r  = f >> 3;
            int k4 = (f & 7) * 4;
            int rg = row0 + r;
            float4 v = make_float4(0.f, 0.f, 0.f, 0.f);
            float sc = 0.0f;
            if (rg < n) {
                v = *(const float4*)&srcp[(size_t)rg * 128 + kb + k4];
                sc = rowscale[rg];
            }
            float vv[4] = {v.x, v.y, v.z, v.w};
            #pragma unroll
            for (int j = 0; j < 4; j++) {
                float t = vv[j];
                if (LEAKY) t = lrelu(t);
                As[k4 + j][r] = t * sc;
            }
        }
        // B tile: 32 k x 128 cols (1024 float4, 4 per thread)
        #pragma unroll
        for (int q = 0; q < 4; q++) {
            int f  = tid + q * 256;
            int kk = f >> 5;
            int cc = (f & 31) * 4;
            *(float4*)&Bs[kk][cc] = *(const float4*)&W[(size_t)(k0 + kk) * 128 + cc];
        }
        __syncthreads();
        #pragma unroll
        for (int kk = 0; kk < 32; kk++) {
            float4 a  = *(const float4*)&As[kk][tr * 4];
            float4 b0 = *(const float4*)&Bs[kk][tc * 8];
            float4 b1 = *(const float4*)&Bs[kk][tc * 8 + 4];
            float av[4] = {a.x, a.y, a.z, a.w};
            float bv[8] = {b0.x, b0.y, b0.z, b0.w, b1.x, b1.y, b1.z, b1.w};
            #pragma unroll
            for (int r = 0; r < 4; r++)
                #pragma unroll
                for (int c = 0; c < 8; c++)
                    acc[r][c] = fmaf(av[r], bv[c], acc[r][c]);
        }
        __syncthreads();
    }
    #pragma unroll
    for (int r = 0; r < 4; r++) {
        int rg = row0 + tr * 4 + r;
        if (rg < n) {
            *(float4*)&Y[(size_t)rg * 128 + tc * 8]     = make_float4(acc[r][0], acc[r][1], acc[r][2], acc[r][3]);
            *(float4*)&Y[(size_t)rg * 128 + tc * 8 + 4] = make_float4(acc[r][4], acc[r][5], acc[r][6], acc[r][7]);
        }
    }
}

// ---------------- CSR SpMM aggregate + epilogue fusion ----------------
// MODE 0: conv1, branch v  -> xhat = agg*in_norm+b+gid ; out[:,128:256]  = 0.5*leaky(xhat)
// MODE 1: conv1, branch t  -> xhat = ...               ; out[:,128:256] += 0.5*leaky(xhat)
// MODE 2: conv2, branch v  ->                            out[:,256:384]  = 0.5*xhat2
// MODE 3: conv2, branch t  ->                            out[:,256:384] += 0.5*xhat2
template<int MODE>
__global__ void k_spmm(const float* __restrict__ y, const int* __restrict__ rp,
                       const int* __restrict__ col, const float* __restrict__ inrm,
                       const float* __restrict__ bias, const float* __restrict__ id_emb,
                       const int* __restrict__ dst_ids, float* __restrict__ xhat,
                       float* __restrict__ out, int n) {
    int gtid = blockIdx.x * blockDim.x + threadIdx.x;
    int row  = gtid >> 6;
    int lane = gtid & 63;
    if (row >= n) return;
    int c = lane * 2;
    float ax = 0.0f, ay = 0.0f;
    int e0 = rp[row], e1 = rp[row + 1];
    for (int e = e0; e < e1; e++) {
        int s = col[e];
        float2 v = *(const float2*)&y[(size_t)s * 128 + c];
        ax += v.x; ay += v.y;
    }
    float w = inrm[row];
    int g = dst_ids[row];
    float2 ge = *(const float2*)&id_emb[(size_t)g * 128 + c];
    float2 bi = *(const float2*)&bias[c];
    float vx = ax * w + bi.x + ge.x;
    float vy = ay * w + bi.y + ge.y;
    if (MODE < 2) {
        *(float2*)&xhat[(size_t)row * 128 + c] = make_float2(vx, vy);
        float ox = 0.5f * lrelu(vx), oy = 0.5f * lrelu(vy);
        float* o = &out[(size_t)row * 384 + 128 + c];
        if (MODE == 0) { o[0] = ox; o[1] = oy; }
        else           { o[0] += ox; o[1] += oy; }
    } else {
        float* o = &out[(size_t)row * 384 + 256 + c];
        if (MODE == 2) { o[0] = 0.5f * vx; o[1] = 0.5f * vy; }
        else           { o[0] += 0.5f * vx; o[1] += 0.5f * vy; }
    }
}

extern "C" void kernel_launch(void* const* d_in, const int* in_sizes, int n_in,
                              void* d_out, int out_size, void* d_ws, size_t ws_size,
                              hipStream_t stream) {
    const float* x      = (const float*)d_in[0];
    const float* id_emb = (const float*)d_in[1];
    const float* Wv0    = (const float*)d_in[2];
    const float* bv0    = (const float*)d_in[3];
    const float* Wv1    = (const float*)d_in[4];
    const float* bv1    = (const float*)d_in[5];
    const float* Wt0    = (const float*)d_in[6];
    const float* bt0    = (const float*)d_in[7];
    const float* Wt1    = (const float*)d_in[8];
    const float* bt1    = (const float*)d_in[9];
    const int*   src    = (const int*)d_in[10];
    const int*   dst    = (const int*)d_in[11];
    const int*   dsti   = (const int*)d_in[12];
    const int E = in_sizes[10];
    const int N = in_sizes[12];
    float* out = (float*)d_out;

    char* p = (char*)d_ws;
    float* xn   = (float*)p; p += (size_t)N * 128 * 4;
    float* y    = (float*)p; p += (size_t)N * 128 * 4;
    float* xhat = (float*)p; p += (size_t)N * 128 * 4;
    float* onrm = (float*)p; p += (size_t)N * 4;
    float* inrm = (float*)p; p += (size_t)N * 4;
    int* deg_out = (int*)p;  p += (size_t)N * 4;
    int* deg_in  = (int*)p;  p += (size_t)N * 4;
    int* cursor  = (int*)p;  p += (size_t)N * 4;
    int* row_ptr = (int*)p;  p += (size_t)(N + 1) * 4;
    int* col     = (int*)p;  p += (size_t)E * 4;

    // deg_out, deg_in, cursor are contiguous: one async zero-fill
    hipMemsetAsync(deg_out, 0, (size_t)N * 3 * 4, stream);

    int be = (E + 255) / 256;
    int bn = (N + 255) / 256;
    int bw = (N * 64 + 255) / 256;   // one wave per row
    int bg = (N + 63) / 64;

    k_degrees<<<be, 256, 0, stream>>>(src, dst, deg_out, deg_in, E);
    k_norms  <<<bn, 256, 0, stream>>>(deg_out, deg_in, onrm, inrm, N);
    k_scan   <<<1, 1024, 0, stream>>>(deg_in, row_ptr, N);
    k_fill   <<<be, 256, 0, stream>>>(src, dst, row_ptr, cursor, col, E);
    k_normx  <<<bw, 256, 0, stream>>>(x, xn, out, N);

    // branch v
    k_gemm<128, false><<<bg, 256, 0, stream>>>(xn, nullptr, Wv0, onrm, y, N);
    k_spmm<0>         <<<bw, 256, 0, stream>>>(y, row_ptr, col, inrm, bv0, id_emb, dsti, xhat, out, N);
    k_gemm<256, true> <<<bg, 256, 0, stream>>>(xn, xhat, Wv1, onrm, y, N);
    k_spmm<2>         <<<bw, 256, 0, stream>>>(y, row_ptr, col, inrm, bv1, id_emb, dsti, xhat, out, N);
    // branch t
    k_gemm<128, false><<<bg, 256, 0, stream>>>(xn, nullptr, Wt0, onrm, y, N);
    k_spmm<1>         <<<bw, 256, 0, stream>>>(y, row_ptr, col, inrm, bt0, id_emb, dsti, xhat, out, N);
    k_gemm<256, true> <<<bg, 256, 0, stream>>>(xn, xhat, Wt1, onrm, y, N);
    k_spmm<3>         <<<bw, 256, 0, stream>>>(y, row_ptr, col, inrm, bt1, id_emb, dsti, xhat, out, N);
}

// Round 2
// 592.565 us; speedup vs baseline: 1.5068x; 1.5068x over previous
//
#include <hip/hip_runtime.h>
#include <math.h>

// MMGCN restructured: GEMM pushed through the (linear) aggregation.
//   z1  = A . (xn*onrm)                      [shared by v,t]   -> conv1 GEMM K=128
//   zlx = A . leaky(xn*onrm)                 [shared by v,t]   -> conv2 top half
//   zx  = A . leaky(xhat_{v,t}*onrm) interleaved               -> conv2 bottom half
//   out256 = ([zlx | zx] @ B2)*in_norm + 0.5(b1v+b1t) + gid    -> one K=384 GEMM
// Gather buffers in bf16 (halves cache-fill traffic of the random gathers).

typedef unsigned int uint;
typedef unsigned short ushort;

__device__ __forceinline__ float lrelu(float v) { return v >= 0.0f ? v : 0.01f * v; }
__device__ __forceinline__ float bf2f(uint us) { return __uint_as_float(us << 16); }
__device__ __forceinline__ ushort f2bf(float f) {
    uint u = __float_as_uint(f);
    u += 0x7fffu + ((u >> 16) & 1u);   // round-to-nearest-even
    return (ushort)(u >> 16);
}

// ---------------- degree histograms ----------------
__global__ void k_degrees(const int* __restrict__ src, const int* __restrict__ dst,
                          int* __restrict__ deg_out, int* __restrict__ deg_in, int E) {
    int e = blockIdx.x * blockDim.x + threadIdx.x;
    if (e < E) {
        atomicAdd(&deg_out[src[e]], 1);
        atomicAdd(&deg_in[dst[e]], 1);
    }
}

__global__ void k_norms(const int* __restrict__ deg_out, const int* __restrict__ deg_in,
                        float* __restrict__ onrm, float* __restrict__ inrm, int n) {
    int i = blockIdx.x * blockDim.x + threadIdx.x;
    if (i < n) {
        onrm[i] = 1.0f / sqrtf((float)max(deg_out[i], 1));
        inrm[i] = 1.0f / sqrtf((float)max(deg_in[i], 1));
    }
}

// ---------------- single-block prefix scan (deg_in -> row_ptr) ----------------
__global__ void k_scan(const int* __restrict__ deg, int* __restrict__ row_ptr, int n) {
    __shared__ int wsum[16];
    __shared__ int wpre[16];
    int lane = threadIdx.x & 63;
    int wid  = threadIdx.x >> 6;
    int carry = 0;
    if (threadIdx.x == 0) row_ptr[0] = 0;
    for (int base = 0; base < n; base += 1024) {
        int i = base + (int)threadIdx.x;
        int v = (i < n) ? deg[i] : 0;
        int s = v;
        #pragma unroll
        for (int off = 1; off < 64; off <<= 1) {
            int t = __shfl_up(s, off, 64);
            if (lane >= off) s += t;
        }
        if (lane == 63) wsum[wid] = s;
        __syncthreads();
        if (wid == 0) {
            int wv = (lane < 16) ? wsum[lane] : 0;
            int ss = wv;
            #pragma unroll
            for (int off = 1; off < 16; off <<= 1) {
                int t = __shfl_up(ss, off, 64);
                if (lane >= off) ss += t;
            }
            if (lane < 16) wpre[lane] = ss - wv;
        }
        __syncthreads();
        int incl = s + wpre[wid];
        if (i < n) row_ptr[i + 1] = carry + incl;
        carry += wpre[15] + wsum[15];
        __syncthreads();
    }
}

__global__ void k_fill(const int* __restrict__ src, const int* __restrict__ dst,
                       const int* __restrict__ row_ptr, int* __restrict__ cursor,
                       int* __restrict__ col, int E) {
    int e = blockIdx.x * blockDim.x + threadIdx.x;
    if (e < E) {
        int d = dst[e];
        int pos = atomicAdd(&cursor[d], 1);
        col[row_ptr[d] + pos] = src[e];
    }
}

// ---------------- weight prep: interleave/stack on device ----------------
__global__ void k_wprep(const float* __restrict__ Wv0, const float* __restrict__ Wt0,
                        const float* __restrict__ Wv1, const float* __restrict__ Wt1,
                        const float* __restrict__ bv0, const float* __restrict__ bt0,
                        const float* __restrict__ bv1, const float* __restrict__ bt1,
                        float* __restrict__ Wcat0, float* __restrict__ B2,
                        float* __restrict__ bias_cat, float* __restrict__ bias2) {
    int t = blockIdx.x * blockDim.x + threadIdx.x;
    if (t < 128 * 256) {               // Wcat0[k][2j+b] = Wb0[k][j]
        int k = t >> 8, c = t & 255;
        int j = c >> 1;
        Wcat0[t] = (c & 1) ? Wt0[k * 128 + j] : Wv0[k * 128 + j];
    }
    if (t < 384 * 128) {               // B2: rows 0:128 = 0.5(Wv1t+Wt1t); rows 128+2k+b = 0.5 Wb1[128+k]
        int r = t >> 7, c = t & 127;
        float v;
        if (r < 128) v = 0.5f * (Wv1[r * 128 + c] + Wt1[r * 128 + c]);
        else {
            int k = (r - 128) >> 1, b = (r - 128) & 1;
            v = 0.5f * (b ? Wt1[(128 + k) * 128 + c] : Wv1[(128 + k) * 128 + c]);
        }
        B2[t] = v;
    }
    if (t < 256) bias_cat[t] = (t & 1) ? bt0[t >> 1] : bv0[t >> 1];
    if (t < 128) bias2[t] = 0.5f * (bv1[t] + bt1[t]);
}

// ---------------- row L2-normalize x; out[:,0:128] = leaky(xn); xn_sc = xn*onrm (bf16) -------
__global__ void k_normx(const float* __restrict__ x, const float* __restrict__ onrm,
                        ushort* __restrict__ xn_sc, float* __restrict__ out, int n) {
    int gtid = blockIdx.x * blockDim.x + threadIdx.x;
    int row  = gtid >> 6;
    int lane = gtid & 63;
    if (row >= n) return;
    int c = lane * 2;
    float2 v = *(const float2*)&x[(size_t)row * 128 + c];
    float s = v.x * v.x + v.y * v.y;
    #pragma unroll
    for (int off = 1; off < 64; off <<= 1) s += __shfl_xor(s, off, 64);
    float scale = 1.0f / fmaxf(sqrtf(s), 1e-12f);
    float nx = v.x * scale, ny = v.y * scale;
    *(float2*)&out[(size_t)row * 384 + c] = make_float2(lrelu(nx), lrelu(ny));
    float so = onrm[row];
    uint p = (uint)f2bf(nx * so) | ((uint)f2bf(ny * so) << 16);
    *(uint*)&xn_sc[(size_t)row * 128 + c] = p;
}

// ---------------- gather pass 1: z1 = A.xn_sc ; zlx = A.leaky(xn_sc)  (both bf16) -------
__global__ void k_agg1(const ushort* __restrict__ xn_sc, const int* __restrict__ rp,
                       const int* __restrict__ col, ushort* __restrict__ z1,
                       ushort* __restrict__ zbig, int n) {
    int gtid = blockIdx.x * blockDim.x + threadIdx.x;
    int row  = gtid >> 6;
    int lane = gtid & 63;
    if (row >= n) return;
    int c = lane * 2;
    float zx = 0.f, zy = 0.f, lx = 0.f, ly = 0.f;
    int e0 = rp[row], e1 = rp[row + 1];
    int e = e0;
    for (; e + 1 < e1; e += 2) {
        int s0 = col[e], s1 = col[e + 1];
        uint v0 = *(const uint*)&xn_sc[(size_t)s0 * 128 + c];
        uint v1 = *(const uint*)&xn_sc[(size_t)s1 * 128 + c];
        float ax = bf2f(v0 & 0xffffu), ay = bf2f(v0 >> 16);
        float bx = bf2f(v1 & 0xffffu), by = bf2f(v1 >> 16);
        zx += ax + bx; zy += ay + by;
        lx += lrelu(ax) + lrelu(bx); ly += lrelu(ay) + lrelu(by);
    }
    if (e < e1) {
        uint v0 = *(const uint*)&xn_sc[(size_t)col[e] * 128 + c];
        float ax = bf2f(v0 & 0xffffu), ay = bf2f(v0 >> 16);
        zx += ax; zy += ay; lx += lrelu(ax); ly += lrelu(ay);
    }
    *(uint*)&z1[(size_t)row * 128 + c]  = (uint)f2bf(zx) | ((uint)f2bf(zy) << 16);
    *(uint*)&zbig[(size_t)row * 384 + c] = (uint)f2bf(lx) | ((uint)f2bf(ly) << 16);
}

// ---------------- gather pass 2: zx_inter = A.xhat_sc  (256-wide, bf16) ----------------
__global__ void k_agg2(const ushort* __restrict__ xhat_sc, const int* __restrict__ rp,
                       const int* __restrict__ col, ushort* __restrict__ zbig, int n) {
    int gtid = blockIdx.x * blockDim.x + threadIdx.x;
    int row  = gtid >> 6;
    int lane = gtid & 63;
    if (row >= n) return;
    int c = lane * 4;
    float a0 = 0.f, a1 = 0.f, a2 = 0.f, a3 = 0.f;
    int e0 = rp[row], e1 = rp[row + 1];
    int e = e0;
    for (; e + 1 < e1; e += 2) {
        int s0 = col[e], s1 = col[e + 1];
        uint2 v0 = *(const uint2*)&xhat_sc[(size_t)s0 * 256 + c];
        uint2 v1 = *(const uint2*)&xhat_sc[(size_t)s1 * 256 + c];
        a0 += bf2f(v0.x & 0xffffu) + bf2f(v1.x & 0xffffu);
        a1 += bf2f(v0.x >> 16)     + bf2f(v1.x >> 16);
        a2 += bf2f(v0.y & 0xffffu) + bf2f(v1.y & 0xffffu);
        a3 += bf2f(v0.y >> 16)     + bf2f(v1.y >> 16);
    }
    if (e < e1) {
        uint2 v0 = *(const uint2*)&xhat_sc[(size_t)col[e] * 256 + c];
        a0 += bf2f(v0.x & 0xffffu); a1 += bf2f(v0.x >> 16);
        a2 += bf2f(v0.y & 0xffffu); a3 += bf2f(v0.y >> 16);
    }
    uint2 p;
    p.x = (uint)f2bf(a0) | ((uint)f2bf(a1) << 16);
    p.y = (uint)f2bf(a2) | ((uint)f2bf(a3) << 16);
    *(uint2*)&zbig[(size_t)row * 384 + 128 + c] = p;
}

// ---------------- tiled GEMM: C = A(bf16) @ B(f32), 128x128 tile, 8x8/thread -------------
// EPI==1 (conv1): t_b = acc*in_norm + bias_cat + gid  (cols interleaved v,t)
//                 out[:,128+j] = 0.5(leaky(t_v)+leaky(t_t)); xhat_sc = bf16(leaky(t_b)*onrm)
// EPI==2 (conv2): out[:,256+c] = acc*in_norm + bias2 + gid
template<int K, int LDA, int LDB, int EPI>
__global__ __launch_bounds__(256) void k_gemm(
    const ushort* __restrict__ A, const float* __restrict__ B,
    const float* __restrict__ inrm, const float* __restrict__ onrm,
    const int* __restrict__ dsti, const float* __restrict__ id_emb,
    const float* __restrict__ bias, ushort* __restrict__ xhat_sc,
    float* __restrict__ out, int n)
{
    __shared__ float As[32][132];   // [k][row], padded
    __shared__ float Bs[32][128];   // [k][col]
    int tid = threadIdx.x;
    int tr = tid >> 4;              // 0..15: rows {tr*4..+3} and {64+tr*4..+3}
    int tc = tid & 15;              // 0..15: cols {tc*4..+3} and {64+tc*4..+3}
    int row0 = blockIdx.x * 128;
    int cgBase = blockIdx.y * 128;

    float acc[8][8];
    #pragma unroll
    for (int i = 0; i < 8; i++)
        #pragma unroll
        for (int j = 0; j < 8; j++) acc[i][j] = 0.0f;

    for (int k0 = 0; k0 < K; k0 += 32) {
        #pragma unroll
        for (int h = 0; h < 4; h++) {           // A: 128 rows x 32 k (bf16), transposed into LDS
            int f = tid + h * 256;
            int r = f >> 3, k4 = (f & 7) * 4;
            int rg = row0 + r;
            uint2 v = make_uint2(0u, 0u);
            if (rg < n) v = *(const uint2*)&A[(size_t)rg * LDA + k0 + k4];
            As[k4 + 0][r] = bf2f(v.x & 0xffffu);
            As[k4 + 1][r] = bf2f(v.x >> 16);
            As[k4 + 2][r] = bf2f(v.y & 0xffffu);
            As[k4 + 3][r] = bf2f(v.y >> 16);
        }
        #pragma unroll
        for (int q = 0; q < 4; q++) {           // B: 32 k x 128 cols (f32)
            int f = tid + q * 256;
            int kk = f >> 5, cc = (f & 31) * 4;
            *(float4*)&Bs[kk][cc] = *(const float4*)&B[(size_t)(k0 + kk) * LDB + cgBase + cc];
        }
        __syncthreads();
        #pragma unroll
        for (int kk = 0; kk < 32; kk++) {
            float4 a0 = *(const float4*)&As[kk][tr * 4];
            float4 a1 = *(const float4*)&As[kk][64 + tr * 4];
            float4 b0 = *(const float4*)&Bs[kk][tc * 4];
            float4 b1 = *(const float4*)&Bs[kk][64 + tc * 4];
            float av[8] = {a0.x, a0.y, a0.z, a0.w, a1.x, a1.y, a1.z, a1.w};
            float bv[8] = {b0.x, b0.y, b0.z, b0.w, b1.x, b1.y, b1.z, b1.w};
            #pragma unroll
            for (int i = 0; i < 8; i++)
                #pragma unroll
                for (int j = 0; j < 8; j++)
                    acc[i][j] = fmaf(av[i], bv[j], acc[i][j]);
        }
        __syncthreads();
    }

    #pragma unroll
    for (int ri = 0; ri < 8; ri++) {
        int rg = row0 + (ri >> 2) * 64 + tr * 4 + (ri & 3);
        if (rg >= n) continue;
        float win = inrm[rg];
        int g = dsti[rg];
        if (EPI == 1) {
            float won = onrm[rg];
            #pragma unroll
            for (int ch = 0; ch < 2; ch++) {
                int cg = cgBase + ch * 64 + tc * 4;       // 4 interleaved cols = 2 (v,t) pairs
                int j0 = cg >> 1;
                float2 ge = *(const float2*)&id_emb[(size_t)g * 128 + j0];
                float tv0 = acc[ri][ch * 4 + 0] * win + bias[cg + 0] + ge.x;
                float tt0 = acc[ri][ch * 4 + 1] * win + bias[cg + 1] + ge.x;
                float tv1 = acc[ri][ch * 4 + 2] * win + bias[cg + 2] + ge.y;
                float tt1 = acc[ri][ch * 4 + 3] * win + bias[cg + 3] + ge.y;
                float lv0 = lrelu(tv0), lt0 = lrelu(tt0);
                float lv1 = lrelu(tv1), lt1 = lrelu(tt1);
                *(float2*)&out[(size_t)rg * 384 + 128 + j0] =
                    make_float2(0.5f * (lv0 + lt0), 0.5f * (lv1 + lt1));
                uint2 p;
                p.x = (uint)f2bf(lv0 * won) | ((uint)f2bf(lt0 * won) << 16);
                p.y = (uint)f2bf(lv1 * won) | ((uint)f2bf(lt1 * won) << 16);
                *(uint2*)&xhat_sc[(size_t)rg * 256 + cg] = p;
            }
        } else {
            #pragma unroll
            for (int ch = 0; ch < 2; ch++) {
                int cg = ch * 64 + tc * 4;
                float4 ge = *(const float4*)&id_emb[(size_t)g * 128 + cg];
                float4 o;
                o.x = acc[ri][ch * 4 + 0] * win + bias[cg + 0] + ge.x;
                o.y = acc[ri][ch * 4 + 1] * win + bias[cg + 1] + ge.y;
                o.z = acc[ri][ch * 4 + 2] * win + bias[cg + 2] + ge.z;
                o.w = acc[ri][ch * 4 + 3] * win + bias[cg + 3] + ge.w;
                *(float4*)&out[(size_t)rg * 384 + 256 + cg] = o;
            }
        }
    }
}

extern "C" void kernel_launch(void* const* d_in, const int* in_sizes, int n_in,
                              void* d_out, int out_size, void* d_ws, size_t ws_size,
                              hipStream_t stream) {
    const float* x      = (const float*)d_in[0];
    const float* id_emb = (const float*)d_in[1];
    const float* Wv0    = (const float*)d_in[2];
    const float* bv0    = (const float*)d_in[3];
    const float* Wv1    = (const float*)d_in[4];
    const float* bv1    = (const float*)d_in[5];
    const float* Wt0    = (const float*)d_in[6];
    const float* bt0    = (const float*)d_in[7];
    const float* Wt1    = (const float*)d_in[8];
    const float* bt1    = (const float*)d_in[9];
    const int*   src    = (const int*)d_in[10];
    const int*   dst    = (const int*)d_in[11];
    const int*   dsti   = (const int*)d_in[12];
    const int E = in_sizes[10];
    const int N = in_sizes[12];
    float* out = (float*)d_out;

    char* p = (char*)d_ws;
    ushort* xn_sc   = (ushort*)p; p += (size_t)N * 128 * 2;
    ushort* xhat_sc = (ushort*)p; p += (size_t)N * 256 * 2;
    ushort* z1      = (ushort*)p; p += (size_t)N * 128 * 2;
    ushort* zbig    = (ushort*)p; p += (size_t)N * 384 * 2;
    float* Wcat0    = (float*)p;  p += 128 * 256 * 4;
    float* B2       = (float*)p;  p += 384 * 128 * 4;
    float* bias_cat = (float*)p;  p += 256 * 4;
    float* bias2    = (float*)p;  p += 128 * 4;
    float* onrm     = (float*)p;  p += (size_t)N * 4;
    float* inrm     = (float*)p;  p += (size_t)N * 4;
    int* deg_out    = (int*)p;    p += (size_t)N * 4;
    int* deg_in     = (int*)p;    p += (size_t)N * 4;
    int* cursor     = (int*)p;    p += (size_t)N * 4;
    int* row_ptr    = (int*)p;    p += (size_t)(N + 1) * 4;
    int* col        = (int*)p;    p += (size_t)E * 4;

    hipMemsetAsync(deg_out, 0, (size_t)N * 3 * 4, stream);   // deg_out|deg_in|cursor contiguous

    int be = (E + 255) / 256;
    int bn = (N + 255) / 256;
    int bw = (N * 64 + 255) / 256;          // one wave per row
    int bg = (N + 127) / 128;               // 128-row GEMM tiles

    k_degrees<<<be, 256, 0, stream>>>(src, dst, deg_out, deg_in, E);
    k_norms  <<<bn, 256, 0, stream>>>(deg_out, deg_in, onrm, inrm, N);
    k_scan   <<<1, 1024, 0, stream>>>(deg_in, row_ptr, N);
    k_fill   <<<be, 256, 0, stream>>>(src, dst, row_ptr, cursor, col, E);
    k_wprep  <<<192, 256, 0, stream>>>(Wv0, Wt0, Wv1, Wt1, bv0, bt0, bv1, bt1,
                                       Wcat0, B2, bias_cat, bias2);
    k_normx  <<<bw, 256, 0, stream>>>(x, onrm, xn_sc, out, N);

    k_agg1<<<bw, 256, 0, stream>>>(xn_sc, row_ptr, col, z1, zbig, N);
    k_gemm<128, 128, 256, 1><<<dim3(bg, 2), 256, 0, stream>>>(
        z1, Wcat0, inrm, onrm, dsti, id_emb, bias_cat, xhat_sc, out, N);
    k_agg2<<<bw, 256, 0, stream>>>(xhat_sc, row_ptr, col, zbig, N);
    k_gemm<384, 384, 128, 2><<<dim3(bg, 1), 256, 0, stream>>>(
        zbig, B2, inrm, onrm, dsti, id_emb, bias2, nullptr, out, N);
}

// Round 4
// 531.871 us; speedup vs baseline: 1.6788x; 1.1141x over previous
//
#include <hip/hip_runtime.h>
#include <math.h>

// MMGCN: GEMM pushed through the (linear) aggregation + bf16 MFMA GEMMs.
//   z1  = A . (xn*onrm)                      [shared by v,t]   -> conv1 GEMM K=128 (MFMA)
//   zlx = A . leaky(xn*onrm)                 [shared by v,t]   -> conv2 top half
//   zx  = A . leaky(xhat_{v,t}*onrm) interleaved               -> conv2 bottom half
//   out256 = ([zlx | zx] @ B2)*in_norm + 0.5(b1v+b1t) + gid    -> one K=384 GEMM (MFMA)

typedef unsigned int uint;
typedef unsigned short ushort;
using bf16x8 = __attribute__((ext_vector_type(8))) short;
using f32x4  = __attribute__((ext_vector_type(4))) float;

__device__ __forceinline__ float lrelu(float v) { return v >= 0.0f ? v : 0.01f * v; }
__device__ __forceinline__ float bf2f(uint us) { return __uint_as_float(us << 16); }
__device__ __forceinline__ ushort f2bf(float f) {
    uint u = __float_as_uint(f);
    u += 0x7fffu + ((u >> 16) & 1u);   // round-to-nearest-even
    return (ushort)(u >> 16);
}

// ---------------- degree histograms ----------------
__global__ void k_degrees(const int* __restrict__ src, const int* __restrict__ dst,
                          int* __restrict__ deg_out, int* __restrict__ deg_in, int E) {
    int e = blockIdx.x * blockDim.x + threadIdx.x;
    if (e < E) {
        atomicAdd(&deg_out[src[e]], 1);
        atomicAdd(&deg_in[dst[e]], 1);
    }
}

__global__ void k_norms(const int* __restrict__ deg_out, const int* __restrict__ deg_in,
                        float* __restrict__ onrm, float* __restrict__ inrm, int n) {
    int i = blockIdx.x * blockDim.x + threadIdx.x;
    if (i < n) {
        onrm[i] = 1.0f / sqrtf((float)max(deg_out[i], 1));
        inrm[i] = 1.0f / sqrtf((float)max(deg_in[i], 1));
    }
}

// ---------------- single-block prefix scan (deg_in -> row_ptr) ----------------
__global__ void k_scan(const int* __restrict__ deg, int* __restrict__ row_ptr, int n) {
    __shared__ int wsum[16];
    __shared__ int wpre[16];
    int lane = threadIdx.x & 63;
    int wid  = threadIdx.x >> 6;
    int carry = 0;
    if (threadIdx.x == 0) row_ptr[0] = 0;
    for (int base = 0; base < n; base += 1024) {
        int i = base + (int)threadIdx.x;
        int v = (i < n) ? deg[i] : 0;
        int s = v;
        #pragma unroll
        for (int off = 1; off < 64; off <<= 1) {
            int t = __shfl_up(s, off, 64);
            if (lane >= off) s += t;
        }
        if (lane == 63) wsum[wid] = s;
        __syncthreads();
        if (wid == 0) {
            int wv = (lane < 16) ? wsum[lane] : 0;
            int ss = wv;
            #pragma unroll
            for (int off = 1; off < 16; off <<= 1) {
                int t = __shfl_up(ss, off, 64);
                if (lane >= off) ss += t;
            }
            if (lane < 16) wpre[lane] = ss - wv;
        }
        __syncthreads();
        int incl = s + wpre[wid];
        if (i < n) row_ptr[i + 1] = carry + incl;
        carry += wpre[15] + wsum[15];
        __syncthreads();
    }
}

__global__ void k_fill(const int* __restrict__ src, const int* __restrict__ dst,
                       const int* __restrict__ row_ptr, int* __restrict__ cursor,
                       int* __restrict__ col, int E) {
    int e = blockIdx.x * blockDim.x + threadIdx.x;
    if (e < E) {
        int d = dst[e];
        int pos = atomicAdd(&cursor[d], 1);
        col[row_ptr[d] + pos] = src[e];
    }
}

// ---------------- weight prep: transpose + interleave/stack, to bf16 ----------------
// W1T [256 cols][128 k]: col 2j+b of conv1 = Wb0[:, j]   (b: 0=v, 1=t)
// W2T [128 cols][384 k]: k 0:128 = 0.5(Wv1+Wt1)[k]; k 128+2q+b = 0.5 Wb1[128+q]
__global__ void k_wprep(const float* __restrict__ Wv0, const float* __restrict__ Wt0,
                        const float* __restrict__ Wv1, const float* __restrict__ Wt1,
                        const float* __restrict__ bv0, const float* __restrict__ bt0,
                        const float* __restrict__ bv1, const float* __restrict__ bt1,
                        ushort* __restrict__ W1T, ushort* __restrict__ W2T,
                        float* __restrict__ bias_cat, float* __restrict__ bias2) {
    int t = blockIdx.x * blockDim.x + threadIdx.x;
    if (t < 256 * 128) {
        int c = t >> 7, k = t & 127;
        float v = (c & 1) ? Wt0[k * 128 + (c >> 1)] : Wv0[k * 128 + (c >> 1)];
        W1T[c * 128 + k] = f2bf(v);
    }
    if (t < 128 * 384) {
        int c = t / 384, r = t % 384;
        float v;
        if (r < 128) v = 0.5f * (Wv1[r * 128 + c] + Wt1[r * 128 + c]);
        else {
            int q = (r - 128) >> 1;
            v = 0.5f * (((r - 128) & 1) ? Wt1[(128 + q) * 128 + c] : Wv1[(128 + q) * 128 + c]);
        }
        W2T[c * 384 + r] = f2bf(v);
    }
    if (t < 256) bias_cat[t] = (t & 1) ? bt0[t >> 1] : bv0[t >> 1];
    if (t < 128) bias2[t] = 0.5f * (bv1[t] + bt1[t]);
}

// ---------------- row L2-normalize x; out[:,0:128] = leaky(xn); xn_sc = xn*onrm (bf16) -------
__global__ void k_normx(const float* __restrict__ x, const float* __restrict__ onrm,
                        ushort* __restrict__ xn_sc, float* __restrict__ out, int n) {
    int gtid = blockIdx.x * blockDim.x + threadIdx.x;
    int row  = gtid >> 6;
    int lane = gtid & 63;
    if (row >= n) return;
    int c = lane * 2;
    float2 v = *(const float2*)&x[(size_t)row * 128 + c];
    float s = v.x * v.x + v.y * v.y;
    #pragma unroll
    for (int off = 1; off < 64; off <<= 1) s += __shfl_xor(s, off, 64);
    float scale = 1.0f / fmaxf(sqrtf(s), 1e-12f);
    float nx = v.x * scale, ny = v.y * scale;
    *(float2*)&out[(size_t)row * 384 + c] = make_float2(lrelu(nx), lrelu(ny));
    float so = onrm[row];
    uint p = (uint)f2bf(nx * so) | ((uint)f2bf(ny * so) << 16);
    *(uint*)&xn_sc[(size_t)row * 128 + c] = p;
}

// ---------------- gather pass 1: z1 = A.xn_sc ; zlx = A.leaky(xn_sc)  (both bf16) -------
__global__ void k_agg1(const ushort* __restrict__ xn_sc, const int* __restrict__ rp,
                       const int* __restrict__ col, ushort* __restrict__ z1,
                       ushort* __restrict__ zbig, int n) {
    int gtid = blockIdx.x * blockDim.x + threadIdx.x;
    int row  = gtid >> 6;
    int lane = gtid & 63;
    if (row >= n) return;
    int c = lane * 2;
    float zx = 0.f, zy = 0.f, lx = 0.f, ly = 0.f;
    int e0 = rp[row], e1 = rp[row + 1];
    int e = e0;
    for (; e + 1 < e1; e += 2) {
        int s0 = col[e], s1 = col[e + 1];
        uint v0 = *(const uint*)&xn_sc[(size_t)s0 * 128 + c];
        uint v1 = *(const uint*)&xn_sc[(size_t)s1 * 128 + c];
        float ax = bf2f(v0 & 0xffffu), ay = bf2f(v0 >> 16);
        float bx = bf2f(v1 & 0xffffu), by = bf2f(v1 >> 16);
        zx += ax + bx; zy += ay + by;
        lx += lrelu(ax) + lrelu(bx); ly += lrelu(ay) + lrelu(by);
    }
    if (e < e1) {
        uint v0 = *(const uint*)&xn_sc[(size_t)col[e] * 128 + c];
        float ax = bf2f(v0 & 0xffffu), ay = bf2f(v0 >> 16);
        zx += ax; zy += ay; lx += lrelu(ax); ly += lrelu(ay);
    }
    *(uint*)&z1[(size_t)row * 128 + c]  = (uint)f2bf(zx) | ((uint)f2bf(zy) << 16);
    *(uint*)&zbig[(size_t)row * 384 + c] = (uint)f2bf(lx) | ((uint)f2bf(ly) << 16);
}

// ---------------- gather pass 2: zx_inter = A.xhat_sc  (256-wide, bf16) ----------------
__global__ void k_agg2(const ushort* __restrict__ xhat_sc, const int* __restrict__ rp,
                       const int* __restrict__ col, ushort* __restrict__ zbig, int n) {
    int gtid = blockIdx.x * blockDim.x + threadIdx.x;
    int row  = gtid >> 6;
    int lane = gtid & 63;
    if (row >= n) return;
    int c = lane * 4;
    float a0 = 0.f, a1 = 0.f, a2 = 0.f, a3 = 0.f;
    int e0 = rp[row], e1 = rp[row + 1];
    int e = e0;
    for (; e + 1 < e1; e += 2) {
        int s0 = col[e], s1 = col[e + 1];
        uint2 v0 = *(const uint2*)&xhat_sc[(size_t)s0 * 256 + c];
        uint2 v1 = *(const uint2*)&xhat_sc[(size_t)s1 * 256 + c];
        a0 += bf2f(v0.x & 0xffffu) + bf2f(v1.x & 0xffffu);
        a1 += bf2f(v0.x >> 16)     + bf2f(v1.x >> 16);
        a2 += bf2f(v0.y & 0xffffu) + bf2f(v1.y & 0xffffu);
        a3 += bf2f(v0.y >> 16)     + bf2f(v1.y >> 16);
    }
    if (e < e1) {
        uint2 v0 = *(const uint2*)&xhat_sc[(size_t)col[e] * 256 + c];
        a0 += bf2f(v0.x & 0xffffu); a1 += bf2f(v0.x >> 16);
        a2 += bf2f(v0.y & 0xffffu); a3 += bf2f(v0.y >> 16);
    }
    uint2 p;
    p.x = (uint)f2bf(a0) | ((uint)f2bf(a1) << 16);
    p.y = (uint)f2bf(a2) | ((uint)f2bf(a3) << 16);
    *(uint2*)&zbig[(size_t)row * 384 + 128 + c] = p;
}

// ---------------- MFMA GEMM: C = A(bf16) @ WT(bf16)^T, 128x128 tile, BK=64 ----------------
// 4 waves in 2x2 grid; each wave computes 64x64 via 4x4 fragments of mfma_f32_16x16x32_bf16.
// C/D layout (gfx950, m89-verified): col=lane&15, row=4*(lane>>4)+reg.
// A/B operand slot permutations cancel (symmetric k-mapping), so contiguous-8 reads are valid.
// EPI==1 (conv1): t_b = acc*in_norm + bias_cat[cg] + gid[cg>>1]  (cols interleaved v,t)
//                 out[:,128+j0] = 0.5(leaky(t_v)+leaky(t_t));  xhat_sc = bf16(leaky(t)*onrm)
// EPI==2 (conv2): out[:,256+c] = acc*in_norm + bias2[c] + gid[c]
template<int K, int LDA, int EPI>
__global__ __launch_bounds__(256) void k_gemm(
    const ushort* __restrict__ A, const ushort* __restrict__ WT,
    const float* __restrict__ inrm, const float* __restrict__ onrm,
    const int* __restrict__ dsti, const float* __restrict__ id_emb,
    const float* __restrict__ bias, ushort* __restrict__ xhat_sc,
    float* __restrict__ out, int n)
{
    __shared__ ushort As[128][72];   // row stride 144B: 2-way bank aliasing (free), 16B aligned
    __shared__ ushort Bs[128][72];
    int tid  = threadIdx.x;
    int lane = tid & 63;
    int w    = tid >> 6;
    int wm   = w >> 1, wn = w & 1;
    int row0 = blockIdx.x * 128;
    int colbase = blockIdx.y * 128;
    int lr = lane & 15;
    int lk = lane >> 4;

    f32x4 acc[4][4];
    f32x4 zero = {0.f, 0.f, 0.f, 0.f};
    #pragma unroll
    for (int m = 0; m < 4; m++)
        #pragma unroll
        for (int nn = 0; nn < 4; nn++) acc[m][nn] = zero;

    for (int k0 = 0; k0 < K; k0 += 64) {
        // stage A (128 rows x 64 k) and B (128 cols x 64 k), 16B (8 bf16) per thread per pass
        #pragma unroll
        for (int pass = 0; pass < 4; pass++) {
            int chunk = tid + pass * 256;       // 0..1023
            int r = chunk >> 3, c16 = (chunk & 7) * 8;
            int rg = row0 + r;
            uint4 av = make_uint4(0u, 0u, 0u, 0u);
            if (rg < n) av = *(const uint4*)&A[(size_t)rg * LDA + k0 + c16];
            *(uint4*)&As[r][c16] = av;
            *(uint4*)&Bs[r][c16] = *(const uint4*)&WT[(size_t)(colbase + r) * K + k0 + c16];
        }
        __syncthreads();
        #pragma unroll
        for (int kk = 0; kk < 2; kk++) {
            int koff = kk * 32 + lk * 8;
            bf16x8 af[4], bf[4];
            #pragma unroll
            for (int m = 0; m < 4; m++)
                af[m] = *(const bf16x8*)&As[wm * 64 + m * 16 + lr][koff];
            #pragma unroll
            for (int nn = 0; nn < 4; nn++)
                bf[nn] = *(const bf16x8*)&Bs[wn * 64 + nn * 16 + lr][koff];
            #pragma unroll
            for (int m = 0; m < 4; m++)
                #pragma unroll
                for (int nn = 0; nn < 4; nn++)
                    acc[m][nn] = __builtin_amdgcn_mfma_f32_16x16x32_bf16(af[m], bf[nn], acc[m][nn], 0, 0, 0);
        }
        __syncthreads();
    }

    // epilogue
    #pragma unroll
    for (int m = 0; m < 4; m++) {
        int rb = row0 + wm * 64 + m * 16 + lk * 4;
        float win[4], won[4]; int gv[4];
        #pragma unroll
        for (int j = 0; j < 4; j++) {
            int r = rb + j;
            bool ok = r < n;
            win[j] = ok ? inrm[r] : 0.f;
            gv[j]  = ok ? dsti[r] : 0;
            if (EPI == 1) won[j] = ok ? onrm[r] : 0.f;
        }
        #pragma unroll
        for (int nn = 0; nn < 4; nn++) {
            int cg = colbase + wn * 64 + nn * 16 + lr;
            float bi = bias[cg];
            if (EPI == 1) {
                int j0 = cg >> 1;
                #pragma unroll
                for (int j = 0; j < 4; j++) {
                    int r = rb + j;
                    float t = acc[m][nn][j] * win[j] + bi + id_emb[(size_t)gv[j] * 128 + j0];
                    float lv = lrelu(t);
                    float po = __shfl_xor(lv, 1, 64);
                    if (((cg & 1) == 0) && r < n) {
                        out[(size_t)r * 384 + 128 + j0] = 0.5f * (lv + po);
                        uint pk = (uint)f2bf(lv * won[j]) | ((uint)f2bf(po * won[j]) << 16);
                        *(uint*)&xhat_sc[(size_t)r * 256 + cg] = pk;
                    }
                }
            } else {
                #pragma unroll
                for (int j = 0; j < 4; j++) {
                    int r = rb + j;
                    if (r < n) {
                        float t = acc[m][nn][j] * win[j] + bi + id_emb[(size_t)gv[j] * 128 + cg];
                        out[(size_t)r * 384 + 256 + cg] = t;
                    }
                }
            }
        }
    }
}

extern "C" void kernel_launch(void* const* d_in, const int* in_sizes, int n_in,
                              void* d_out, int out_size, void* d_ws, size_t ws_size,
                              hipStream_t stream) {
    const float* x      = (const float*)d_in[0];
    const float* id_emb = (const float*)d_in[1];
    const float* Wv0    = (const float*)d_in[2];
    const float* bv0    = (const float*)d_in[3];
    const float* Wv1    = (const float*)d_in[4];
    const float* bv1    = (const float*)d_in[5];
    const float* Wt0    = (const float*)d_in[6];
    const float* bt0    = (const float*)d_in[7];
    const float* Wt1    = (const float*)d_in[8];
    const float* bt1    = (const float*)d_in[9];
    const int*   src    = (const int*)d_in[10];
    const int*   dst    = (const int*)d_in[11];
    const int*   dsti   = (const int*)d_in[12];
    const int E = in_sizes[10];
    const int N = in_sizes[12];
    float* out = (float*)d_out;

    char* p = (char*)d_ws;
    ushort* xn_sc   = (ushort*)p; p += (size_t)N * 128 * 2;
    ushort* xhat_sc = (ushort*)p; p += (size_t)N * 256 * 2;
    ushort* z1      = (ushort*)p; p += (size_t)N * 128 * 2;
    ushort* zbig    = (ushort*)p; p += (size_t)N * 384 * 2;
    ushort* W1T     = (ushort*)p; p += 256 * 128 * 2;
    ushort* W2T     = (ushort*)p; p += 128 * 384 * 2;
    float* bias_cat = (float*)p;  p += 256 * 4;
    float* bias2    = (float*)p;  p += 128 * 4;
    float* onrm     = (float*)p;  p += (size_t)N * 4;
    float* inrm     = (float*)p;  p += (size_t)N * 4;
    int* deg_out    = (int*)p;    p += (size_t)N * 4;
    int* deg_in     = (int*)p;    p += (size_t)N * 4;
    int* cursor     = (int*)p;    p += (size_t)N * 4;
    int* row_ptr    = (int*)p;    p += (size_t)(N + 1) * 4;
    int* col        = (int*)p;    p += (size_t)E * 4;

    hipMemsetAsync(deg_out, 0, (size_t)N * 3 * 4, stream);   // deg_out|deg_in|cursor contiguous

    int be = (E + 255) / 256;
    int bn = (N + 255) / 256;
    int bw = (N * 64 + 255) / 256;          // one wave per row
    int bg = (N + 127) / 128;               // 128-row GEMM tiles

    k_degrees<<<be, 256, 0, stream>>>(src, dst, deg_out, deg_in, E);
    k_norms  <<<bn, 256, 0, stream>>>(deg_out, deg_in, onrm, inrm, N);
    k_scan   <<<1, 1024, 0, stream>>>(deg_in, row_ptr, N);
    k_fill   <<<be, 256, 0, stream>>>(src, dst, row_ptr, cursor, col, E);
    k_wprep  <<<192, 256, 0, stream>>>(Wv0, Wt0, Wv1, Wt1, bv0, bt0, bv1, bt1,
                                       W1T, W2T, bias_cat, bias2);
    k_normx  <<<bw, 256, 0, stream>>>(x, onrm, xn_sc, out, N);

    k_agg1<<<bw, 256, 0, stream>>>(xn_sc, row_ptr, col, z1, zbig, N);
    k_gemm<128, 128, 1><<<dim3(bg, 2), 256, 0, stream>>>(
        z1, W1T, inrm, onrm, dsti, id_emb, bias_cat, xhat_sc, out, N);
    k_agg2<<<bw, 256, 0, stream>>>(xhat_sc, row_ptr, col, zbig, N);
    k_gemm<384, 384, 2><<<dim3(bg, 1), 256, 0, stream>>>(
        zbig, W2T, inrm, onrm, dsti, id_emb, bias2, nullptr, out, N);
}

// Round 5
// 520.172 us; speedup vs baseline: 1.7165x; 1.0225x over previous
//
#include <hip/hip_runtime.h>
#include <math.h>

// MMGCN: GEMM pushed through the (linear) aggregation + bf16 MFMA GEMMs.
//   z1  = A . (xn*onrm)                      [shared by v,t]   -> conv1 GEMM K=128 (MFMA)
//   zlx = A . leaky(xn*onrm)                 [shared by v,t]   -> conv2 top half
//   zx  = A . leaky(xhat_{v,t}*onrm) interleaved               -> conv2 bottom half
//   out256 = ([zlx | zx] @ B2)*in_norm + 0.5(b1v+b1t) + gid    -> one K=384 GEMM (MFMA)
// gid = id_emb[dst_ids] materialized densely once (f32) so GEMM epilogues are coalesced.

typedef unsigned int uint;
typedef unsigned short ushort;
using bf16x8 = __attribute__((ext_vector_type(8))) short;
using f32x4  = __attribute__((ext_vector_type(4))) float;

__device__ __forceinline__ float lrelu(float v) { return v >= 0.0f ? v : 0.01f * v; }
__device__ __forceinline__ float bf2f(uint us) { return __uint_as_float(us << 16); }
__device__ __forceinline__ ushort f2bf(float f) {
    uint u = __float_as_uint(f);
    u += 0x7fffu + ((u >> 16) & 1u);   // round-to-nearest-even
    return (ushort)(u >> 16);
}

// ---------------- degree histograms ----------------
__global__ void k_degrees(const int* __restrict__ src, const int* __restrict__ dst,
                          int* __restrict__ deg_out, int* __restrict__ deg_in, int E) {
    int e = blockIdx.x * blockDim.x + threadIdx.x;
    if (e < E) {
        atomicAdd(&deg_out[src[e]], 1);
        atomicAdd(&deg_in[dst[e]], 1);
    }
}

__global__ void k_norms(const int* __restrict__ deg_out, const int* __restrict__ deg_in,
                        float* __restrict__ onrm, float* __restrict__ inrm, int n) {
    int i = blockIdx.x * blockDim.x + threadIdx.x;
    if (i < n) {
        onrm[i] = 1.0f / sqrtf((float)max(deg_out[i], 1));
        inrm[i] = 1.0f / sqrtf((float)max(deg_in[i], 1));
    }
}

// ---------------- single-block prefix scan (deg_in -> row_ptr) ----------------
__global__ void k_scan(const int* __restrict__ deg, int* __restrict__ row_ptr, int n) {
    __shared__ int wsum[16];
    __shared__ int wpre[16];
    int lane = threadIdx.x & 63;
    int wid  = threadIdx.x >> 6;
    int carry = 0;
    if (threadIdx.x == 0) row_ptr[0] = 0;
    for (int base = 0; base < n; base += 1024) {
        int i = base + (int)threadIdx.x;
        int v = (i < n) ? deg[i] : 0;
        int s = v;
        #pragma unroll
        for (int off = 1; off < 64; off <<= 1) {
            int t = __shfl_up(s, off, 64);
            if (lane >= off) s += t;
        }
        if (lane == 63) wsum[wid] = s;
        __syncthreads();
        if (wid == 0) {
            int wv = (lane < 16) ? wsum[lane] : 0;
            int ss = wv;
            #pragma unroll
            for (int off = 1; off < 16; off <<= 1) {
                int t = __shfl_up(ss, off, 64);
                if (lane >= off) ss += t;
            }
            if (lane < 16) wpre[lane] = ss - wv;
        }
        __syncthreads();
        int incl = s + wpre[wid];
        if (i < n) row_ptr[i + 1] = carry + incl;
        carry += wpre[15] + wsum[15];
        __syncthreads();
    }
}

__global__ void k_fill(const int* __restrict__ src, const int* __restrict__ dst,
                       const int* __restrict__ row_ptr, int* __restrict__ cursor,
                       int* __restrict__ col, int E) {
    int e = blockIdx.x * blockDim.x + threadIdx.x;
    if (e < E) {
        int d = dst[e];
        int pos = atomicAdd(&cursor[d], 1);
        col[row_ptr[d] + pos] = src[e];
    }
}

// ---------------- weight prep ----------------
// W1T [256 cols][128 k]: cols 0:128 = Wv0 cols; 128:256 = Wt0 cols  (de-interleaved)
// W2T [128 cols][384 k]: k 0:128 = 0.5(Wv1+Wt1); k 128+2q+b = 0.5 Wb1[128+q]  (interleaved)
__global__ void k_wprep(const float* __restrict__ Wv0, const float* __restrict__ Wt0,
                        const float* __restrict__ Wv1, const float* __restrict__ Wt1,
                        const float* __restrict__ bv0, const float* __restrict__ bt0,
                        const float* __restrict__ bv1, const float* __restrict__ bt1,
                        ushort* __restrict__ W1T, ushort* __restrict__ W2T,
                        float* __restrict__ bias_cat, float* __restrict__ bias2) {
    int t = blockIdx.x * blockDim.x + threadIdx.x;
    if (t < 256 * 128) {
        int c = t >> 7, k = t & 127;
        float v = (c < 128) ? Wv0[k * 128 + c] : Wt0[k * 128 + (c - 128)];
        W1T[c * 128 + k] = f2bf(v);
    }
    if (t < 128 * 384) {
        int c = t / 384, r = t % 384;
        float v;
        if (r < 128) v = 0.5f * (Wv1[r * 128 + c] + Wt1[r * 128 + c]);
        else {
            int q = (r - 128) >> 1;
            v = 0.5f * (((r - 128) & 1) ? Wt1[(128 + q) * 128 + c] : Wv1[(128 + q) * 128 + c]);
        }
        W2T[c * 384 + r] = f2bf(v);
    }
    if (t < 256) bias_cat[t] = (t < 128) ? bv0[t] : bt0[t - 128];
    if (t < 128) bias2[t] = 0.5f * (bv1[t] + bt1[t]);
}

// ------- row L2-normalize x; out[:,0:128]=leaky(xn); xn_sc=xn*onrm (bf16); gid densified -------
__global__ void k_normx(const float* __restrict__ x, const float* __restrict__ onrm,
                        const int* __restrict__ dsti, const float* __restrict__ id_emb,
                        ushort* __restrict__ xn_sc, float* __restrict__ gid,
                        float* __restrict__ out, int n) {
    int gtid = blockIdx.x * blockDim.x + threadIdx.x;
    int row  = gtid >> 6;
    int lane = gtid & 63;
    if (row >= n) return;
    int c = lane * 2;
    float2 v = *(const float2*)&x[(size_t)row * 128 + c];
    float s = v.x * v.x + v.y * v.y;
    #pragma unroll
    for (int off = 1; off < 64; off <<= 1) s += __shfl_xor(s, off, 64);
    float scale = 1.0f / fmaxf(sqrtf(s), 1e-12f);
    float nx = v.x * scale, ny = v.y * scale;
    *(float2*)&out[(size_t)row * 384 + c] = make_float2(lrelu(nx), lrelu(ny));
    float so = onrm[row];
    uint p = (uint)f2bf(nx * so) | ((uint)f2bf(ny * so) << 16);
    *(uint*)&xn_sc[(size_t)row * 128 + c] = p;
    // densify id_emb[dsti[row]] -> gid[row]
    int g = dsti[row];
    float2 ge = *(const float2*)&id_emb[(size_t)g * 128 + c];
    *(float2*)&gid[(size_t)row * 128 + c] = ge;
}

// ---------------- gather pass 1: z1 = A.xn_sc ; zlx = A.leaky(xn_sc)  (both bf16) -------
__global__ void k_agg1(const ushort* __restrict__ xn_sc, const int* __restrict__ rp,
                       const int* __restrict__ col, ushort* __restrict__ z1,
                       ushort* __restrict__ zbig, int n) {
    int gtid = blockIdx.x * blockDim.x + threadIdx.x;
    int row  = gtid >> 6;
    int lane = gtid & 63;
    if (row >= n) return;
    int c = lane * 2;
    float zx = 0.f, zy = 0.f, lx = 0.f, ly = 0.f;
    int e0 = rp[row], e1 = rp[row + 1];
    int e = e0;
    for (; e + 1 < e1; e += 2) {
        int s0 = col[e], s1 = col[e + 1];
        uint v0 = *(const uint*)&xn_sc[(size_t)s0 * 128 + c];
        uint v1 = *(const uint*)&xn_sc[(size_t)s1 * 128 + c];
        float ax = bf2f(v0 & 0xffffu), ay = bf2f(v0 >> 16);
        float bx = bf2f(v1 & 0xffffu), by = bf2f(v1 >> 16);
        zx += ax + bx; zy += ay + by;
        lx += lrelu(ax) + lrelu(bx); ly += lrelu(ay) + lrelu(by);
    }
    if (e < e1) {
        uint v0 = *(const uint*)&xn_sc[(size_t)col[e] * 128 + c];
        float ax = bf2f(v0 & 0xffffu), ay = bf2f(v0 >> 16);
        zx += ax; zy += ay; lx += lrelu(ax); ly += lrelu(ay);
    }
    *(uint*)&z1[(size_t)row * 128 + c]  = (uint)f2bf(zx) | ((uint)f2bf(zy) << 16);
    *(uint*)&zbig[(size_t)row * 384 + c] = (uint)f2bf(lx) | ((uint)f2bf(ly) << 16);
}

// ---------------- gather pass 2: zx_inter = A.xhat_sc  (256-wide, bf16) ----------------
__global__ void k_agg2(const ushort* __restrict__ xhat_sc, const int* __restrict__ rp,
                       const int* __restrict__ col, ushort* __restrict__ zbig, int n) {
    int gtid = blockIdx.x * blockDim.x + threadIdx.x;
    int row  = gtid >> 6;
    int lane = gtid & 63;
    if (row >= n) return;
    int c = lane * 4;
    float a0 = 0.f, a1 = 0.f, a2 = 0.f, a3 = 0.f;
    int e0 = rp[row], e1 = rp[row + 1];
    int e = e0;
    for (; e + 1 < e1; e += 2) {
        int s0 = col[e], s1 = col[e + 1];
        uint2 v0 = *(const uint2*)&xhat_sc[(size_t)s0 * 256 + c];
        uint2 v1 = *(const uint2*)&xhat_sc[(size_t)s1 * 256 + c];
        a0 += bf2f(v0.x & 0xffffu) + bf2f(v1.x & 0xffffu);
        a1 += bf2f(v0.x >> 16)     + bf2f(v1.x >> 16);
        a2 += bf2f(v0.y & 0xffffu) + bf2f(v1.y & 0xffffu);
        a3 += bf2f(v0.y >> 16)     + bf2f(v1.y >> 16);
    }
    if (e < e1) {
        uint2 v0 = *(const uint2*)&xhat_sc[(size_t)col[e] * 256 + c];
        a0 += bf2f(v0.x & 0xffffu); a1 += bf2f(v0.x >> 16);
        a2 += bf2f(v0.y & 0xffffu); a3 += bf2f(v0.y >> 16);
    }
    uint2 p;
    p.x = (uint)f2bf(a0) | ((uint)f2bf(a1) << 16);
    p.y = (uint)f2bf(a2) | ((uint)f2bf(a3) << 16);
    *(uint2*)&zbig[(size_t)row * 384 + 128 + c] = p;
}

// ---------------- conv1 MFMA GEMM: 128x256 tile (cols = [v 0:128 | t 128:256]), K=128 -------
// 4 waves 2x2; wave covers rows wm*64+64, v-cols wn*64..+63 AND t-cols 128+wn*64..+63,
// so each lane owns the (v,t) pair of its column -> fully coalesced fused epilogue:
//   tv/tt = acc*in_norm + bias + gid;  out[:,128+c] = 0.5(leaky(tv)+leaky(tt));
//   xhat_sc[r][2c,2c+1] = bf16(leaky(tv)*onrm, leaky(tt)*onrm)   (interleaved for agg2/W2T)
__global__ __launch_bounds__(256) void k_gemm1(
    const ushort* __restrict__ A, const ushort* __restrict__ WT,
    const float* __restrict__ inrm, const float* __restrict__ onrm,
    const float* __restrict__ gid, const float* __restrict__ bias,
    ushort* __restrict__ xhat_sc, float* __restrict__ out, int n)
{
    __shared__ ushort As[128][72];
    __shared__ ushort Bs[256][72];
    int tid  = threadIdx.x;
    int lane = tid & 63;
    int w    = tid >> 6;
    int wm   = w >> 1, wn = w & 1;
    int row0 = blockIdx.x * 128;
    int lr = lane & 15;
    int lk = lane >> 4;

    f32x4 acc[4][8];
    f32x4 zero = {0.f, 0.f, 0.f, 0.f};
    #pragma unroll
    for (int m = 0; m < 4; m++)
        #pragma unroll
        for (int nn = 0; nn < 8; nn++) acc[m][nn] = zero;

    for (int k0 = 0; k0 < 128; k0 += 64) {
        #pragma unroll
        for (int pass = 0; pass < 4; pass++) {        // A: 128 rows x 64 k
            int chunk = tid + pass * 256;
            int r = chunk >> 3, c8 = (chunk & 7) * 8;
            int rg = row0 + r;
            uint4 av = make_uint4(0u, 0u, 0u, 0u);
            if (rg < n) av = *(const uint4*)&A[(size_t)rg * 128 + k0 + c8];
            *(uint4*)&As[r][c8] = av;
        }
        #pragma unroll
        for (int pass = 0; pass < 8; pass++) {        // B: 256 cols x 64 k
            int chunk = tid + pass * 256;
            int r = chunk >> 3, c8 = (chunk & 7) * 8;
            *(uint4*)&Bs[r][c8] = *(const uint4*)&WT[(size_t)r * 128 + k0 + c8];
        }
        __syncthreads();
        #pragma unroll
        for (int kk = 0; kk < 2; kk++) {
            int koff = kk * 32 + lk * 8;
            bf16x8 af[4], bf[8];
            #pragma unroll
            for (int m = 0; m < 4; m++)
                af[m] = *(const bf16x8*)&As[wm * 64 + m * 16 + lr][koff];
            #pragma unroll
            for (int nn = 0; nn < 4; nn++) {
                bf[nn]     = *(const bf16x8*)&Bs[wn * 64 + nn * 16 + lr][koff];
                bf[nn + 4] = *(const bf16x8*)&Bs[128 + wn * 64 + nn * 16 + lr][koff];
            }
            #pragma unroll
            for (int m = 0; m < 4; m++)
                #pragma unroll
                for (int nn = 0; nn < 8; nn++)
                    acc[m][nn] = __builtin_amdgcn_mfma_f32_16x16x32_bf16(af[m], bf[nn], acc[m][nn], 0, 0, 0);
        }
        __syncthreads();
    }

    #pragma unroll
    for (int m = 0; m < 4; m++) {
        int rb = row0 + wm * 64 + m * 16 + lk * 4;
        #pragma unroll
        for (int nn = 0; nn < 4; nn++) {
            int cv = wn * 64 + nn * 16 + lr;          // 0..127
            float biv = bias[cv];
            float bit = bias[128 + cv];
            #pragma unroll
            for (int j = 0; j < 4; j++) {
                int r = rb + j;
                if (r >= n) continue;
                float win = inrm[r];
                float won = onrm[r];
                float ge = gid[(size_t)r * 128 + cv];
                float tv = acc[m][nn][j] * win + biv + ge;
                float tt = acc[m][nn + 4][j] * win + bit + ge;
                float lv = lrelu(tv), lt = lrelu(tt);
                out[(size_t)r * 384 + 128 + cv] = 0.5f * (lv + lt);
                uint pk = (uint)f2bf(lv * won) | ((uint)f2bf(lt * won) << 16);
                *(uint*)&xhat_sc[(size_t)r * 256 + 2 * cv] = pk;
            }
        }
    }
}

// ---------------- conv2 MFMA GEMM: 128x128 tile, K=384; out[:,256+c] = acc*in_norm+b2+gid ----
__global__ __launch_bounds__(256) void k_gemm2(
    const ushort* __restrict__ A, const ushort* __restrict__ WT,
    const float* __restrict__ inrm, const float* __restrict__ gid,
    const float* __restrict__ bias, float* __restrict__ out, int n)
{
    __shared__ ushort As[128][72];
    __shared__ ushort Bs[128][72];
    int tid  = threadIdx.x;
    int lane = tid & 63;
    int w    = tid >> 6;
    int wm   = w >> 1, wn = w & 1;
    int row0 = blockIdx.x * 128;
    int lr = lane & 15;
    int lk = lane >> 4;

    f32x4 acc[4][4];
    f32x4 zero = {0.f, 0.f, 0.f, 0.f};
    #pragma unroll
    for (int m = 0; m < 4; m++)
        #pragma unroll
        for (int nn = 0; nn < 4; nn++) acc[m][nn] = zero;

    for (int k0 = 0; k0 < 384; k0 += 64) {
        #pragma unroll
        for (int pass = 0; pass < 4; pass++) {
            int chunk = tid + pass * 256;
            int r = chunk >> 3, c8 = (chunk & 7) * 8;
            int rg = row0 + r;
            uint4 av = make_uint4(0u, 0u, 0u, 0u);
            if (rg < n) av = *(const uint4*)&A[(size_t)rg * 384 + k0 + c8];
            *(uint4*)&As[r][c8] = av;
            *(uint4*)&Bs[r][c8] = *(const uint4*)&WT[(size_t)r * 384 + k0 + c8];
        }
        __syncthreads();
        #pragma unroll
        for (int kk = 0; kk < 2; kk++) {
            int koff = kk * 32 + lk * 8;
            bf16x8 af[4], bf[4];
            #pragma unroll
            for (int m = 0; m < 4; m++)
                af[m] = *(const bf16x8*)&As[wm * 64 + m * 16 + lr][koff];
            #pragma unroll
            for (int nn = 0; nn < 4; nn++)
                bf[nn] = *(const bf16x8*)&Bs[wn * 64 + nn * 16 + lr][koff];
            #pragma unroll
            for (int m = 0; m < 4; m++)
                #pragma unroll
                for (int nn = 0; nn < 4; nn++)
                    acc[m][nn] = __builtin_amdgcn_mfma_f32_16x16x32_bf16(af[m], bf[nn], acc[m][nn], 0, 0, 0);
        }
        __syncthreads();
    }

    #pragma unroll
    for (int m = 0; m < 4; m++) {
        int rb = row0 + wm * 64 + m * 16 + lk * 4;
        #pragma unroll
        for (int nn = 0; nn < 4; nn++) {
            int cg = wn * 64 + nn * 16 + lr;
            float bi = bias[cg];
            #pragma unroll
            for (int j = 0; j < 4; j++) {
                int r = rb + j;
                if (r >= n) continue;
                float t = acc[m][nn][j] * inrm[r] + bi + gid[(size_t)r * 128 + cg];
                out[(size_t)r * 384 + 256 + cg] = t;
            }
        }
    }
}

extern "C" void kernel_launch(void* const* d_in, const int* in_sizes, int n_in,
                              void* d_out, int out_size, void* d_ws, size_t ws_size,
                              hipStream_t stream) {
    const float* x      = (const float*)d_in[0];
    const float* id_emb = (const float*)d_in[1];
    const float* Wv0    = (const float*)d_in[2];
    const float* bv0    = (const float*)d_in[3];
    const float* Wv1    = (const float*)d_in[4];
    const float* bv1    = (const float*)d_in[5];
    const float* Wt0    = (const float*)d_in[6];
    const float* bt0    = (const float*)d_in[7];
    const float* Wt1    = (const float*)d_in[8];
    const float* bt1    = (const float*)d_in[9];
    const int*   src    = (const int*)d_in[10];
    const int*   dst    = (const int*)d_in[11];
    const int*   dsti   = (const int*)d_in[12];
    const int E = in_sizes[10];
    const int N = in_sizes[12];
    float* out = (float*)d_out;

    char* p = (char*)d_ws;
    ushort* xn_sc   = (ushort*)p; p += (size_t)N * 128 * 2;
    ushort* xhat_sc = (ushort*)p; p += (size_t)N * 256 * 2;
    ushort* z1      = (ushort*)p; p += (size_t)N * 128 * 2;
    ushort* zbig    = (ushort*)p; p += (size_t)N * 384 * 2;
    float*  gid     = (float*)p;  p += (size_t)N * 128 * 4;
    ushort* W1T     = (ushort*)p; p += 256 * 128 * 2;
    ushort* W2T     = (ushort*)p; p += 128 * 384 * 2;
    float* bias_cat = (float*)p;  p += 256 * 4;
    float* bias2    = (float*)p;  p += 128 * 4;
    float* onrm     = (float*)p;  p += (size_t)N * 4;
    float* inrm     = (float*)p;  p += (size_t)N * 4;
    int* deg_out    = (int*)p;    p += (size_t)N * 4;
    int* deg_in     = (int*)p;    p += (size_t)N * 4;
    int* cursor     = (int*)p;    p += (size_t)N * 4;
    int* row_ptr    = (int*)p;    p += (size_t)(N + 1) * 4;
    int* col        = (int*)p;    p += (size_t)E * 4;

    hipMemsetAsync(deg_out, 0, (size_t)N * 3 * 4, stream);   // deg_out|deg_in|cursor contiguous

    int be = (E + 255) / 256;
    int bn = (N + 255) / 256;
    int bw = (N * 64 + 255) / 256;          // one wave per row
    int bg = (N + 127) / 128;               // 128-row GEMM tiles

    k_degrees<<<be, 256, 0, stream>>>(src, dst, deg_out, deg_in, E);
    k_norms  <<<bn, 256, 0, stream>>>(deg_out, deg_in, onrm, inrm, N);
    k_scan   <<<1, 1024, 0, stream>>>(deg_in, row_ptr, N);
    k_fill   <<<be, 256, 0, stream>>>(src, dst, row_ptr, cursor, col, E);
    k_wprep  <<<192, 256, 0, stream>>>(Wv0, Wt0, Wv1, Wt1, bv0, bt0, bv1, bt1,
                                       W1T, W2T, bias_cat, bias2);
    k_normx  <<<bw, 256, 0, stream>>>(x, onrm, dsti, id_emb, xn_sc, gid, out, N);

    k_agg1 <<<bw, 256, 0, stream>>>(xn_sc, row_ptr, col, z1, zbig, N);
    k_gemm1<<<bg, 256, 0, stream>>>(z1, W1T, inrm, onrm, gid, bias_cat, xhat_sc, out, N);
    k_agg2 <<<bw, 256, 0, stream>>>(xhat_sc, row_ptr, col, zbig, N);
    k_gemm2<<<bg, 256, 0, stream>>>(zbig, W2T, inrm, gid, bias2, out, N);
}

// Round 6
// 484.092 us; speedup vs baseline: 1.8445x; 1.0745x over previous
//
#include <hip/hip_runtime.h>
#include <math.h>

// MMGCN: GEMM pushed through the (linear) aggregation + LDS-free bf16 MFMA GEMMs.
//   z1  = A . (xn*onrm)                      [shared by v,t]   -> conv1 GEMM K=128 (MFMA)
//   zlx = A . leaky(xn*onrm)                 [shared by v,t]   -> conv2 top half
//   zx  = A . leaky(xhat_{v,t}*onrm) interleaved               -> conv2 bottom half
//   out256 = ([zlx | zx] @ B2)*in_norm + 0.5(b1v+b1t) + gid    -> one K=384 GEMM (MFMA)
// GEMMs load MFMA fragments DIRECTLY from global (A frag = 16 contiguous bytes/lane;
// W matrices are 64-96 KB -> L2-resident). No LDS, no barriers -> latency hidden by
// free-running waves. gid = id_emb[dst_ids] densified once, stored bf16.

typedef unsigned int uint;
typedef unsigned short ushort;
using bf16x8 = __attribute__((ext_vector_type(8))) short;
using f32x4  = __attribute__((ext_vector_type(4))) float;

__device__ __forceinline__ float lrelu(float v) { return v >= 0.0f ? v : 0.01f * v; }
__device__ __forceinline__ float bf2f(uint us) { return __uint_as_float(us << 16); }
__device__ __forceinline__ ushort f2bf(float f) {
    uint u = __float_as_uint(f);
    u += 0x7fffu + ((u >> 16) & 1u);   // round-to-nearest-even
    return (ushort)(u >> 16);
}

// ---------------- degree histograms ----------------
__global__ void k_degrees(const int* __restrict__ src, const int* __restrict__ dst,
                          int* __restrict__ deg_out, int* __restrict__ deg_in, int E) {
    int e = blockIdx.x * blockDim.x + threadIdx.x;
    if (e < E) {
        atomicAdd(&deg_out[src[e]], 1);
        atomicAdd(&deg_in[dst[e]], 1);
    }
}

__global__ void k_norms(const int* __restrict__ deg_out, const int* __restrict__ deg_in,
                        float* __restrict__ onrm, float* __restrict__ inrm, int n) {
    int i = blockIdx.x * blockDim.x + threadIdx.x;
    if (i < n) {
        onrm[i] = 1.0f / sqrtf((float)max(deg_out[i], 1));
        inrm[i] = 1.0f / sqrtf((float)max(deg_in[i], 1));
    }
}

// ---------------- single-block prefix scan (deg_in -> row_ptr) ----------------
__global__ void k_scan(const int* __restrict__ deg, int* __restrict__ row_ptr, int n) {
    __shared__ int wsum[16];
    __shared__ int wpre[16];
    int lane = threadIdx.x & 63;
    int wid  = threadIdx.x >> 6;
    int carry = 0;
    if (threadIdx.x == 0) row_ptr[0] = 0;
    for (int base = 0; base < n; base += 1024) {
        int i = base + (int)threadIdx.x;
        int v = (i < n) ? deg[i] : 0;
        int s = v;
        #pragma unroll
        for (int off = 1; off < 64; off <<= 1) {
            int t = __shfl_up(s, off, 64);
            if (lane >= off) s += t;
        }
        if (lane == 63) wsum[wid] = s;
        __syncthreads();
        if (wid == 0) {
            int wv = (lane < 16) ? wsum[lane] : 0;
            int ss = wv;
            #pragma unroll
            for (int off = 1; off < 16; off <<= 1) {
                int t = __shfl_up(ss, off, 64);
                if (lane >= off) ss += t;
            }
            if (lane < 16) wpre[lane] = ss - wv;
        }
        __syncthreads();
        int incl = s + wpre[wid];
        if (i < n) row_ptr[i + 1] = carry + incl;
        carry += wpre[15] + wsum[15];
        __syncthreads();
    }
}

__global__ void k_fill(const int* __restrict__ src, const int* __restrict__ dst,
                       const int* __restrict__ row_ptr, int* __restrict__ cursor,
                       int* __restrict__ col, int E) {
    int e = blockIdx.x * blockDim.x + threadIdx.x;
    if (e < E) {
        int d = dst[e];
        int pos = atomicAdd(&cursor[d], 1);
        col[row_ptr[d] + pos] = src[e];
    }
}

// ---------------- weight prep ----------------
// W1T [256 cols][128 k]: cols 0:128 = Wv0 cols; 128:256 = Wt0 cols  (de-interleaved)
// W2T [128 cols][384 k]: k 0:128 = 0.5(Wv1+Wt1); k 128+2q+b = 0.5 Wb1[128+q]  (interleaved)
__global__ void k_wprep(const float* __restrict__ Wv0, const float* __restrict__ Wt0,
                        const float* __restrict__ Wv1, const float* __restrict__ Wt1,
                        const float* __restrict__ bv0, const float* __restrict__ bt0,
                        const float* __restrict__ bv1, const float* __restrict__ bt1,
                        ushort* __restrict__ W1T, ushort* __restrict__ W2T,
                        float* __restrict__ bias_cat, float* __restrict__ bias2) {
    int t = blockIdx.x * blockDim.x + threadIdx.x;
    if (t < 256 * 128) {
        int c = t >> 7, k = t & 127;
        float v = (c < 128) ? Wv0[k * 128 + c] : Wt0[k * 128 + (c - 128)];
        W1T[c * 128 + k] = f2bf(v);
    }
    if (t < 128 * 384) {
        int c = t / 384, r = t % 384;
        float v;
        if (r < 128) v = 0.5f * (Wv1[r * 128 + c] + Wt1[r * 128 + c]);
        else {
            int q = (r - 128) >> 1;
            v = 0.5f * (((r - 128) & 1) ? Wt1[(128 + q) * 128 + c] : Wv1[(128 + q) * 128 + c]);
        }
        W2T[c * 384 + r] = f2bf(v);
    }
    if (t < 256) bias_cat[t] = (t < 128) ? bv0[t] : bt0[t - 128];
    if (t < 128) bias2[t] = 0.5f * (bv1[t] + bt1[t]);
}

// ------- row L2-normalize x; out[:,0:128]=leaky(xn); xn_sc=xn*onrm (bf16); gid bf16 -------
__global__ void k_normx(const float* __restrict__ x, const float* __restrict__ onrm,
                        const int* __restrict__ dsti, const float* __restrict__ id_emb,
                        ushort* __restrict__ xn_sc, ushort* __restrict__ gid,
                        float* __restrict__ out, int n) {
    int gtid = blockIdx.x * blockDim.x + threadIdx.x;
    int row  = gtid >> 6;
    int lane = gtid & 63;
    if (row >= n) return;
    int c = lane * 2;
    float2 v = *(const float2*)&x[(size_t)row * 128 + c];
    float s = v.x * v.x + v.y * v.y;
    #pragma unroll
    for (int off = 1; off < 64; off <<= 1) s += __shfl_xor(s, off, 64);
    float scale = 1.0f / fmaxf(sqrtf(s), 1e-12f);
    float nx = v.x * scale, ny = v.y * scale;
    *(float2*)&out[(size_t)row * 384 + c] = make_float2(lrelu(nx), lrelu(ny));
    float so = onrm[row];
    uint p = (uint)f2bf(nx * so) | ((uint)f2bf(ny * so) << 16);
    *(uint*)&xn_sc[(size_t)row * 128 + c] = p;
    // densify id_emb[dsti[row]] -> gid[row] (bf16)
    int g = dsti[row];
    float2 ge = *(const float2*)&id_emb[(size_t)g * 128 + c];
    uint pg = (uint)f2bf(ge.x) | ((uint)f2bf(ge.y) << 16);
    *(uint*)&gid[(size_t)row * 128 + c] = pg;
}

// ---------------- gather pass 1: z1 = A.xn_sc ; zlx = A.leaky(xn_sc)  (both bf16) -------
__global__ void k_agg1(const ushort* __restrict__ xn_sc, const int* __restrict__ rp,
                       const int* __restrict__ col, ushort* __restrict__ z1,
                       ushort* __restrict__ zbig, int n) {
    int gtid = blockIdx.x * blockDim.x + threadIdx.x;
    int row  = gtid >> 6;
    int lane = gtid & 63;
    if (row >= n) return;
    int c = lane * 2;
    float zx = 0.f, zy = 0.f, lx = 0.f, ly = 0.f;
    int e0 = rp[row], e1 = rp[row + 1];
    int e = e0;
    for (; e + 1 < e1; e += 2) {
        int s0 = col[e], s1 = col[e + 1];
        uint v0 = *(const uint*)&xn_sc[(size_t)s0 * 128 + c];
        uint v1 = *(const uint*)&xn_sc[(size_t)s1 * 128 + c];
        float ax = bf2f(v0 & 0xffffu), ay = bf2f(v0 >> 16);
        float bx = bf2f(v1 & 0xffffu), by = bf2f(v1 >> 16);
        zx += ax + bx; zy += ay + by;
        lx += lrelu(ax) + lrelu(bx); ly += lrelu(ay) + lrelu(by);
    }
    if (e < e1) {
        uint v0 = *(const uint*)&xn_sc[(size_t)col[e] * 128 + c];
        float ax = bf2f(v0 & 0xffffu), ay = bf2f(v0 >> 16);
        zx += ax; zy += ay; lx += lrelu(ax); ly += lrelu(ay);
    }
    *(uint*)&z1[(size_t)row * 128 + c]  = (uint)f2bf(zx) | ((uint)f2bf(zy) << 16);
    *(uint*)&zbig[(size_t)row * 384 + c] = (uint)f2bf(lx) | ((uint)f2bf(ly) << 16);
}

// ---------------- gather pass 2: zx_inter = A.xhat_sc  (256-wide, bf16) ----------------
__global__ void k_agg2(const ushort* __restrict__ xhat_sc, const int* __restrict__ rp,
                       const int* __restrict__ col, ushort* __restrict__ zbig, int n) {
    int gtid = blockIdx.x * blockDim.x + threadIdx.x;
    int row  = gtid >> 6;
    int lane = gtid & 63;
    if (row >= n) return;
    int c = lane * 4;
    float a0 = 0.f, a1 = 0.f, a2 = 0.f, a3 = 0.f;
    int e0 = rp[row], e1 = rp[row + 1];
    int e = e0;
    for (; e + 1 < e1; e += 2) {
        int s0 = col[e], s1 = col[e + 1];
        uint2 v0 = *(const uint2*)&xhat_sc[(size_t)s0 * 256 + c];
        uint2 v1 = *(const uint2*)&xhat_sc[(size_t)s1 * 256 + c];
        a0 += bf2f(v0.x & 0xffffu) + bf2f(v1.x & 0xffffu);
        a1 += bf2f(v0.x >> 16)     + bf2f(v1.x >> 16);
        a2 += bf2f(v0.y & 0xffffu) + bf2f(v1.y & 0xffffu);
        a3 += bf2f(v0.y >> 16)     + bf2f(v1.y >> 16);
    }
    if (e < e1) {
        uint2 v0 = *(const uint2*)&xhat_sc[(size_t)col[e] * 256 + c];
        a0 += bf2f(v0.x & 0xffffu); a1 += bf2f(v0.x >> 16);
        a2 += bf2f(v0.y & 0xffffu); a3 += bf2f(v0.y >> 16);
    }
    uint2 p;
    p.x = (uint)f2bf(a0) | ((uint)f2bf(a1) << 16);
    p.y = (uint)f2bf(a2) | ((uint)f2bf(a3) << 16);
    *(uint2*)&zbig[(size_t)row * 384 + 128 + c] = p;
}

// ---------------- conv1 MFMA GEMM, LDS-free: 128 rows x 256 cols per block ----------------
// 4 waves 2x2; wave = 64 rows x (64 v-cols + matching 64 t-cols). Fragments loaded
// straight from global: A frag lane addr = A[row(lane&15)][k0 + 8*(lane>>4)] (16B).
// Epilogue: tv/tt = acc*in_norm + bias + gid; out[:,128+c] = 0.5(leaky(tv)+leaky(tt));
//           xhat_sc[r][2c,2c+1] = bf16(leaky(tv)*onrm, leaky(tt)*onrm)
__global__ __launch_bounds__(256) void k_gemm1(
    const ushort* __restrict__ A, const ushort* __restrict__ WT,
    const float* __restrict__ inrm, const float* __restrict__ onrm,
    const ushort* __restrict__ gid, const float* __restrict__ bias,
    ushort* __restrict__ xhat_sc, float* __restrict__ out, int n)
{
    int tid  = threadIdx.x;
    int lane = tid & 63;
    int w    = tid >> 6;
    int wm   = w >> 1, wn = w & 1;
    int row0 = blockIdx.x * 128;
    int lr = lane & 15;
    int lk = lane >> 4;

    f32x4 acc[4][8];
    f32x4 zero = {0.f, 0.f, 0.f, 0.f};
    #pragma unroll
    for (int m = 0; m < 4; m++)
        #pragma unroll
        for (int nn = 0; nn < 8; nn++) acc[m][nn] = zero;

    int rg[4]; bool ok[4];
    #pragma unroll
    for (int m = 0; m < 4; m++) { rg[m] = row0 + wm * 64 + m * 16 + lr; ok[m] = rg[m] < n; }
    bf16x8 zf = {0, 0, 0, 0, 0, 0, 0, 0};

    #pragma unroll
    for (int ks = 0; ks < 4; ks++) {
        int koff = ks * 32 + lk * 8;
        bf16x8 af[4], bf[8];
        #pragma unroll
        for (int m = 0; m < 4; m++)
            af[m] = ok[m] ? *(const bf16x8*)&A[(size_t)rg[m] * 128 + koff] : zf;
        #pragma unroll
        for (int nn = 0; nn < 4; nn++) {
            int cv = wn * 64 + nn * 16 + lr;
            bf[nn]     = *(const bf16x8*)&WT[(size_t)cv * 128 + koff];
            bf[nn + 4] = *(const bf16x8*)&WT[(size_t)(128 + cv) * 128 + koff];
        }
        #pragma unroll
        for (int m = 0; m < 4; m++)
            #pragma unroll
            for (int nn = 0; nn < 8; nn++)
                acc[m][nn] = __builtin_amdgcn_mfma_f32_16x16x32_bf16(af[m], bf[nn], acc[m][nn], 0, 0, 0);
    }

    #pragma unroll
    for (int m = 0; m < 4; m++) {
        int rb = row0 + wm * 64 + m * 16 + lk * 4;
        #pragma unroll
        for (int nn = 0; nn < 4; nn++) {
            int cv = wn * 64 + nn * 16 + lr;          // 0..127
            float biv = bias[cv];
            float bit = bias[128 + cv];
            #pragma unroll
            for (int j = 0; j < 4; j++) {
                int r = rb + j;
                if (r >= n) continue;
                float win = inrm[r];
                float won = onrm[r];
                float ge = bf2f((uint)gid[(size_t)r * 128 + cv]);
                float tv = acc[m][nn][j] * win + biv + ge;
                float tt = acc[m][nn + 4][j] * win + bit + ge;
                float lv = lrelu(tv), lt = lrelu(tt);
                out[(size_t)r * 384 + 128 + cv] = 0.5f * (lv + lt);
                uint pk = (uint)f2bf(lv * won) | ((uint)f2bf(lt * won) << 16);
                *(uint*)&xhat_sc[(size_t)r * 256 + 2 * cv] = pk;
            }
        }
    }
}

// ---------------- conv2 MFMA GEMM, LDS-free: 128x128 tile, K=384 ----------------
__global__ __launch_bounds__(256) void k_gemm2(
    const ushort* __restrict__ A, const ushort* __restrict__ WT,
    const float* __restrict__ inrm, const ushort* __restrict__ gid,
    const float* __restrict__ bias, float* __restrict__ out, int n)
{
    int tid  = threadIdx.x;
    int lane = tid & 63;
    int w    = tid >> 6;
    int wm   = w >> 1, wn = w & 1;
    int row0 = blockIdx.x * 128;
    int lr = lane & 15;
    int lk = lane >> 4;

    f32x4 acc[4][4];
    f32x4 zero = {0.f, 0.f, 0.f, 0.f};
    #pragma unroll
    for (int m = 0; m < 4; m++)
        #pragma unroll
        for (int nn = 0; nn < 4; nn++) acc[m][nn] = zero;

    int rg[4]; bool ok[4];
    #pragma unroll
    for (int m = 0; m < 4; m++) { rg[m] = row0 + wm * 64 + m * 16 + lr; ok[m] = rg[m] < n; }
    bf16x8 zf = {0, 0, 0, 0, 0, 0, 0, 0};

    #pragma unroll
    for (int ks = 0; ks < 12; ks++) {
        int koff = ks * 32 + lk * 8;
        bf16x8 af[4], bf[4];
        #pragma unroll
        for (int m = 0; m < 4; m++)
            af[m] = ok[m] ? *(const bf16x8*)&A[(size_t)rg[m] * 384 + koff] : zf;
        #pragma unroll
        for (int nn = 0; nn < 4; nn++) {
            int cg = wn * 64 + nn * 16 + lr;
            bf[nn] = *(const bf16x8*)&WT[(size_t)cg * 384 + koff];
        }
        #pragma unroll
        for (int m = 0; m < 4; m++)
            #pragma unroll
            for (int nn = 0; nn < 4; nn++)
                acc[m][nn] = __builtin_amdgcn_mfma_f32_16x16x32_bf16(af[m], bf[nn], acc[m][nn], 0, 0, 0);
    }

    #pragma unroll
    for (int m = 0; m < 4; m++) {
        int rb = row0 + wm * 64 + m * 16 + lk * 4;
        #pragma unroll
        for (int nn = 0; nn < 4; nn++) {
            int cg = wn * 64 + nn * 16 + lr;
            float bi = bias[cg];
            #pragma unroll
            for (int j = 0; j < 4; j++) {
                int r = rb + j;
                if (r >= n) continue;
                float ge = bf2f((uint)gid[(size_t)r * 128 + cg]);
                float t = acc[m][nn][j] * inrm[r] + bi + ge;
                out[(size_t)r * 384 + 256 + cg] = t;
            }
        }
    }
}

extern "C" void kernel_launch(void* const* d_in, const int* in_sizes, int n_in,
                              void* d_out, int out_size, void* d_ws, size_t ws_size,
                              hipStream_t stream) {
    const float* x      = (const float*)d_in[0];
    const float* id_emb = (const float*)d_in[1];
    const float* Wv0    = (const float*)d_in[2];
    const float* bv0    = (const float*)d_in[3];
    const float* Wv1    = (const float*)d_in[4];
    const float* bv1    = (const float*)d_in[5];
    const float* Wt0    = (const float*)d_in[6];
    const float* bt0    = (const float*)d_in[7];
    const float* Wt1    = (const float*)d_in[8];
    const float* bt1    = (const float*)d_in[9];
    const int*   src    = (const int*)d_in[10];
    const int*   dst    = (const int*)d_in[11];
    const int*   dsti   = (const int*)d_in[12];
    const int E = in_sizes[10];
    const int N = in_sizes[12];
    float* out = (float*)d_out;

    char* p = (char*)d_ws;
    ushort* xn_sc   = (ushort*)p; p += (size_t)N * 128 * 2;
    ushort* xhat_sc = (ushort*)p; p += (size_t)N * 256 * 2;
    ushort* z1      = (ushort*)p; p += (size_t)N * 128 * 2;
    ushort* zbig    = (ushort*)p; p += (size_t)N * 384 * 2;
    ushort* gid     = (ushort*)p; p += (size_t)N * 128 * 2;
    ushort* W1T     = (ushort*)p; p += 256 * 128 * 2;
    ushort* W2T     = (ushort*)p; p += 128 * 384 * 2;
    float* bias_cat = (float*)p;  p += 256 * 4;
    float* bias2    = (float*)p;  p += 128 * 4;
    float* onrm     = (float*)p;  p += (size_t)N * 4;
    float* inrm     = (float*)p;  p += (size_t)N * 4;
    int* deg_out    = (int*)p;    p += (size_t)N * 4;
    int* deg_in     = (int*)p;    p += (size_t)N * 4;
    int* cursor     = (int*)p;    p += (size_t)N * 4;
    int* row_ptr    = (int*)p;    p += (size_t)(N + 1) * 4;
    int* col        = (int*)p;    p += (size_t)E * 4;

    hipMemsetAsync(deg_out, 0, (size_t)N * 3 * 4, stream);   // deg_out|deg_in|cursor contiguous

    int be = (E + 255) / 256;
    int bn = (N + 255) / 256;
    int bw = (N * 64 + 255) / 256;          // one wave per row
    int bg = (N + 127) / 128;               // 128-row GEMM tiles

    k_degrees<<<be, 256, 0, stream>>>(src, dst, deg_out, deg_in, E);
    k_norms  <<<bn, 256, 0, stream>>>(deg_out, deg_in, onrm, inrm, N);
    k_scan   <<<1, 1024, 0, stream>>>(deg_in, row_ptr, N);
    k_fill   <<<be, 256, 0, stream>>>(src, dst, row_ptr, cursor, col, E);
    k_wprep  <<<192, 256, 0, stream>>>(Wv0, Wt0, Wv1, Wt1, bv0, bt0, bv1, bt1,
                                       W1T, W2T, bias_cat, bias2);
    k_normx  <<<bw, 256, 0, stream>>>(x, onrm, dsti, id_emb, xn_sc, gid, out, N);

    k_agg1 <<<bw, 256, 0, stream>>>(xn_sc, row_ptr, col, z1, zbig, N);
    k_gemm1<<<bg, 256, 0, stream>>>(z1, W1T, inrm, onrm, gid, bias_cat, xhat_sc, out, N);
    k_agg2 <<<bw, 256, 0, stream>>>(xhat_sc, row_ptr, col, zbig, N);
    k_gemm2<<<bg, 256, 0, stream>>>(zbig, W2T, inrm, gid, bias2, out, N);
}

// Round 7
// 404.278 us; speedup vs baseline: 2.2086x; 1.1974x over previous
//
#include <hip/hip_runtime.h>
#include <math.h>

// MMGCN: GEMM pushed through the (linear) aggregation + LDS-free bf16 MFMA GEMMs.
//   z1  = A . (xn*onrm)                      [shared by v,t]   -> conv1 GEMM K=128 (MFMA)
//   zlx = A . leaky(xn*onrm)                 [shared by v,t]   -> conv2 top half
//   zx  = A . leaky(xhat_{v,t}*onrm) interleaved               -> conv2 bottom half
//   out256 = ([zlx | zx] @ B2)*in_norm + 0.5(b1v+b1t) + gid    -> one K=384 GEMM (MFMA)
// GEMMs load MFMA fragments DIRECTLY from global (A frag = 16 contiguous bytes/lane;
// W matrices are 64-96 KB -> L2-resident). No LDS, no barriers.
// Prefix scan (deg_in -> row_ptr) is a 3-kernel multi-block scan (was 93us single-block).

typedef unsigned int uint;
typedef unsigned short ushort;
using bf16x8 = __attribute__((ext_vector_type(8))) short;
using f32x4  = __attribute__((ext_vector_type(4))) float;

__device__ __forceinline__ float lrelu(float v) { return v >= 0.0f ? v : 0.01f * v; }
__device__ __forceinline__ float bf2f(uint us) { return __uint_as_float(us << 16); }
__device__ __forceinline__ ushort f2bf(float f) {
    uint u = __float_as_uint(f);
    u += 0x7fffu + ((u >> 16) & 1u);   // round-to-nearest-even
    return (ushort)(u >> 16);
}

// ---------------- degree histograms ----------------
__global__ void k_degrees(const int* __restrict__ src, const int* __restrict__ dst,
                          int* __restrict__ deg_out, int* __restrict__ deg_in, int E) {
    int e = blockIdx.x * blockDim.x + threadIdx.x;
    if (e < E) {
        atomicAdd(&deg_out[src[e]], 1);
        atomicAdd(&deg_in[dst[e]], 1);
    }
}

__global__ void k_norms(const int* __restrict__ deg_out, const int* __restrict__ deg_in,
                        float* __restrict__ onrm, float* __restrict__ inrm, int n) {
    int i = blockIdx.x * blockDim.x + threadIdx.x;
    if (i < n) {
        onrm[i] = 1.0f / sqrtf((float)max(deg_out[i], 1));
        inrm[i] = 1.0f / sqrtf((float)max(deg_in[i], 1));
    }
}

// ---------------- multi-block prefix scan: deg_in -> row_ptr ----------------
// scan1: per-1024-chunk inclusive scan (chunk-local) + chunk totals
__global__ void k_scan1(const int* __restrict__ deg, int* __restrict__ row_ptr,
                        int* __restrict__ csum, int n) {
    __shared__ int wsum[16];
    __shared__ int wpre[16];
    int lane = threadIdx.x & 63;
    int wid  = threadIdx.x >> 6;
    int i = blockIdx.x * 1024 + threadIdx.x;
    int v = (i < n) ? deg[i] : 0;
    int s = v;
    #pragma unroll
    for (int off = 1; off < 64; off <<= 1) {
        int t = __shfl_up(s, off, 64);
        if (lane >= off) s += t;
    }
    if (lane == 63) wsum[wid] = s;
    __syncthreads();
    if (wid == 0) {
        int wv = (lane < 16) ? wsum[lane] : 0;
        int ss = wv;
        #pragma unroll
        for (int off = 1; off < 16; off <<= 1) {
            int t = __shfl_up(ss, off, 64);
            if (lane >= off) ss += t;
        }
        if (lane < 16) wpre[lane] = ss - wv;
    }
    __syncthreads();
    int incl = s + wpre[wid];
    if (i < n) row_ptr[i + 1] = incl;                        // chunk-local for now
    if (threadIdx.x == 1023) csum[blockIdx.x] = incl;        // chunk total
}

// scan2: single-block inclusive scan of chunk totals (nb <= 1024)
__global__ void k_scan2(int* __restrict__ csum, int nb) {
    __shared__ int wsum[16];
    __shared__ int wpre[16];
    int lane = threadIdx.x & 63;
    int wid  = threadIdx.x >> 6;
    int i = threadIdx.x;
    int v = (i < nb) ? csum[i] : 0;
    int s = v;
    #pragma unroll
    for (int off = 1; off < 64; off <<= 1) {
        int t = __shfl_up(s, off, 64);
        if (lane >= off) s += t;
    }
    if (lane == 63) wsum[wid] = s;
    __syncthreads();
    if (wid == 0) {
        int wv = (lane < 16) ? wsum[lane] : 0;
        int ss = wv;
        #pragma unroll
        for (int off = 1; off < 16; off <<= 1) {
            int t = __shfl_up(ss, off, 64);
            if (lane >= off) ss += t;
        }
        if (lane < 16) wpre[lane] = ss - wv;
    }
    __syncthreads();
    if (i < nb) csum[i] = s + wpre[wid];
}

// scan3: add chunk-prefix offsets; set row_ptr[0]
__global__ void k_scan3(int* __restrict__ row_ptr, const int* __restrict__ csum, int n) {
    int i = blockIdx.x * blockDim.x + threadIdx.x;
    if (i == 0) row_ptr[0] = 0;
    if (i < n) {
        int b = i >> 10;
        if (b > 0) row_ptr[i + 1] += csum[b - 1];
    }
}

__global__ void k_fill(const int* __restrict__ src, const int* __restrict__ dst,
                       const int* __restrict__ row_ptr, int* __restrict__ cursor,
                       int* __restrict__ col, int E) {
    int e = blockIdx.x * blockDim.x + threadIdx.x;
    if (e < E) {
        int d = dst[e];
        int pos = atomicAdd(&cursor[d], 1);
        col[row_ptr[d] + pos] = src[e];
    }
}

// ---------------- weight prep ----------------
// W1T [256 cols][128 k]: cols 0:128 = Wv0 cols; 128:256 = Wt0 cols  (de-interleaved)
// W2T [128 cols][384 k]: k 0:128 = 0.5(Wv1+Wt1); k 128+2q+b = 0.5 Wb1[128+q]  (interleaved)
__global__ void k_wprep(const float* __restrict__ Wv0, const float* __restrict__ Wt0,
                        const float* __restrict__ Wv1, const float* __restrict__ Wt1,
                        const float* __restrict__ bv0, const float* __restrict__ bt0,
                        const float* __restrict__ bv1, const float* __restrict__ bt1,
                        ushort* __restrict__ W1T, ushort* __restrict__ W2T,
                        float* __restrict__ bias_cat, float* __restrict__ bias2) {
    int t = blockIdx.x * blockDim.x + threadIdx.x;
    if (t < 256 * 128) {
        int c = t >> 7, k = t & 127;
        float v = (c < 128) ? Wv0[k * 128 + c] : Wt0[k * 128 + (c - 128)];
        W1T[c * 128 + k] = f2bf(v);
    }
    if (t < 128 * 384) {
        int c = t / 384, r = t % 384;
        float v;
        if (r < 128) v = 0.5f * (Wv1[r * 128 + c] + Wt1[r * 128 + c]);
        else {
            int q = (r - 128) >> 1;
            v = 0.5f * (((r - 128) & 1) ? Wt1[(128 + q) * 128 + c] : Wv1[(128 + q) * 128 + c]);
        }
        W2T[c * 384 + r] = f2bf(v);
    }
    if (t < 256) bias_cat[t] = (t < 128) ? bv0[t] : bt0[t - 128];
    if (t < 128) bias2[t] = 0.5f * (bv1[t] + bt1[t]);
}

// ------- row L2-normalize x; out[:,0:128]=leaky(xn); xn_sc=xn*onrm (bf16); gid bf16 -------
__global__ void k_normx(const float* __restrict__ x, const float* __restrict__ onrm,
                        const int* __restrict__ dsti, const float* __restrict__ id_emb,
                        ushort* __restrict__ xn_sc, ushort* __restrict__ gid,
                        float* __restrict__ out, int n) {
    int gtid = blockIdx.x * blockDim.x + threadIdx.x;
    int row  = gtid >> 6;
    int lane = gtid & 63;
    if (row >= n) return;
    int c = lane * 2;
    float2 v = *(const float2*)&x[(size_t)row * 128 + c];
    float s = v.x * v.x + v.y * v.y;
    #pragma unroll
    for (int off = 1; off < 64; off <<= 1) s += __shfl_xor(s, off, 64);
    float scale = 1.0f / fmaxf(sqrtf(s), 1e-12f);
    float nx = v.x * scale, ny = v.y * scale;
    *(float2*)&out[(size_t)row * 384 + c] = make_float2(lrelu(nx), lrelu(ny));
    float so = onrm[row];
    uint p = (uint)f2bf(nx * so) | ((uint)f2bf(ny * so) << 16);
    *(uint*)&xn_sc[(size_t)row * 128 + c] = p;
    // densify id_emb[dsti[row]] -> gid[row] (bf16)
    int g = dsti[row];
    float2 ge = *(const float2*)&id_emb[(size_t)g * 128 + c];
    uint pg = (uint)f2bf(ge.x) | ((uint)f2bf(ge.y) << 16);
    *(uint*)&gid[(size_t)row * 128 + c] = pg;
}

// ---------------- gather pass 1: z1 = A.xn_sc ; zlx = A.leaky(xn_sc)  (both bf16) -------
__global__ void k_agg1(const ushort* __restrict__ xn_sc, const int* __restrict__ rp,
                       const int* __restrict__ col, ushort* __restrict__ z1,
                       ushort* __restrict__ zbig, int n) {
    int gtid = blockIdx.x * blockDim.x + threadIdx.x;
    int row  = gtid >> 6;
    int lane = gtid & 63;
    if (row >= n) return;
    int c = lane * 2;
    float zx = 0.f, zy = 0.f, lx = 0.f, ly = 0.f;
    int e0 = rp[row], e1 = rp[row + 1];
    int e = e0;
    for (; e + 1 < e1; e += 2) {
        int s0 = col[e], s1 = col[e + 1];
        uint v0 = *(const uint*)&xn_sc[(size_t)s0 * 128 + c];
        uint v1 = *(const uint*)&xn_sc[(size_t)s1 * 128 + c];
        float ax = bf2f(v0 & 0xffffu), ay = bf2f(v0 >> 16);
        float bx = bf2f(v1 & 0xffffu), by = bf2f(v1 >> 16);
        zx += ax + bx; zy += ay + by;
        lx += lrelu(ax) + lrelu(bx); ly += lrelu(ay) + lrelu(by);
    }
    if (e < e1) {
        uint v0 = *(const uint*)&xn_sc[(size_t)col[e] * 128 + c];
        float ax = bf2f(v0 & 0xffffu), ay = bf2f(v0 >> 16);
        zx += ax; zy += ay; lx += lrelu(ax); ly += lrelu(ay);
    }
    *(uint*)&z1[(size_t)row * 128 + c]  = (uint)f2bf(zx) | ((uint)f2bf(zy) << 16);
    *(uint*)&zbig[(size_t)row * 384 + c] = (uint)f2bf(lx) | ((uint)f2bf(ly) << 16);
}

// ---------------- gather pass 2: zx_inter = A.xhat_sc  (256-wide, bf16) ----------------
__global__ void k_agg2(const ushort* __restrict__ xhat_sc, const int* __restrict__ rp,
                       const int* __restrict__ col, ushort* __restrict__ zbig, int n) {
    int gtid = blockIdx.x * blockDim.x + threadIdx.x;
    int row  = gtid >> 6;
    int lane = gtid & 63;
    if (row >= n) return;
    int c = lane * 4;
    float a0 = 0.f, a1 = 0.f, a2 = 0.f, a3 = 0.f;
    int e0 = rp[row], e1 = rp[row + 1];
    int e = e0;
    for (; e + 1 < e1; e += 2) {
        int s0 = col[e], s1 = col[e + 1];
        uint2 v0 = *(const uint2*)&xhat_sc[(size_t)s0 * 256 + c];
        uint2 v1 = *(const uint2*)&xhat_sc[(size_t)s1 * 256 + c];
        a0 += bf2f(v0.x & 0xffffu) + bf2f(v1.x & 0xffffu);
        a1 += bf2f(v0.x >> 16)     + bf2f(v1.x >> 16);
        a2 += bf2f(v0.y & 0xffffu) + bf2f(v1.y & 0xffffu);
        a3 += bf2f(v0.y >> 16)     + bf2f(v1.y >> 16);
    }
    if (e < e1) {
        uint2 v0 = *(const uint2*)&xhat_sc[(size_t)col[e] * 256 + c];
        a0 += bf2f(v0.x & 0xffffu); a1 += bf2f(v0.x >> 16);
        a2 += bf2f(v0.y & 0xffffu); a3 += bf2f(v0.y >> 16);
    }
    uint2 p;
    p.x = (uint)f2bf(a0) | ((uint)f2bf(a1) << 16);
    p.y = (uint)f2bf(a2) | ((uint)f2bf(a3) << 16);
    *(uint2*)&zbig[(size_t)row * 384 + 128 + c] = p;
}

// ---------------- conv1 MFMA GEMM, LDS-free: 128 rows x 256 cols per block ----------------
__global__ __launch_bounds__(256) void k_gemm1(
    const ushort* __restrict__ A, const ushort* __restrict__ WT,
    const float* __restrict__ inrm, const float* __restrict__ onrm,
    const ushort* __restrict__ gid, const float* __restrict__ bias,
    ushort* __restrict__ xhat_sc, float* __restrict__ out, int n)
{
    int tid  = threadIdx.x;
    int lane = tid & 63;
    int w    = tid >> 6;
    int wm   = w >> 1, wn = w & 1;
    int row0 = blockIdx.x * 128;
    int lr = lane & 15;
    int lk = lane >> 4;

    f32x4 acc[4][8];
    f32x4 zero = {0.f, 0.f, 0.f, 0.f};
    #pragma unroll
    for (int m = 0; m < 4; m++)
        #pragma unroll
        for (int nn = 0; nn < 8; nn++) acc[m][nn] = zero;

    int rg[4]; bool ok[4];
    #pragma unroll
    for (int m = 0; m < 4; m++) { rg[m] = row0 + wm * 64 + m * 16 + lr; ok[m] = rg[m] < n; }
    bf16x8 zf = {0, 0, 0, 0, 0, 0, 0, 0};

    #pragma unroll
    for (int ks = 0; ks < 4; ks++) {
        int koff = ks * 32 + lk * 8;
        bf16x8 af[4], bf[8];
        #pragma unroll
        for (int m = 0; m < 4; m++)
            af[m] = ok[m] ? *(const bf16x8*)&A[(size_t)rg[m] * 128 + koff] : zf;
        #pragma unroll
        for (int nn = 0; nn < 4; nn++) {
            int cv = wn * 64 + nn * 16 + lr;
            bf[nn]     = *(const bf16x8*)&WT[(size_t)cv * 128 + koff];
            bf[nn + 4] = *(const bf16x8*)&WT[(size_t)(128 + cv) * 128 + koff];
        }
        #pragma unroll
        for (int m = 0; m < 4; m++)
            #pragma unroll
            for (int nn = 0; nn < 8; nn++)
                acc[m][nn] = __builtin_amdgcn_mfma_f32_16x16x32_bf16(af[m], bf[nn], acc[m][nn], 0, 0, 0);
    }

    #pragma unroll
    for (int m = 0; m < 4; m++) {
        int rb = row0 + wm * 64 + m * 16 + lk * 4;
        #pragma unroll
        for (int nn = 0; nn < 4; nn++) {
            int cv = wn * 64 + nn * 16 + lr;          // 0..127
            float biv = bias[cv];
            float bit = bias[128 + cv];
            #pragma unroll
            for (int j = 0; j < 4; j++) {
                int r = rb + j;
                if (r >= n) continue;
                float win = inrm[r];
                float won = onrm[r];
                float ge = bf2f((uint)gid[(size_t)r * 128 + cv]);
                float tv = acc[m][nn][j] * win + biv + ge;
                float tt = acc[m][nn + 4][j] * win + bit + ge;
                float lv = lrelu(tv), lt = lrelu(tt);
                out[(size_t)r * 384 + 128 + cv] = 0.5f * (lv + lt);
                uint pk = (uint)f2bf(lv * won) | ((uint)f2bf(lt * won) << 16);
                *(uint*)&xhat_sc[(size_t)r * 256 + 2 * cv] = pk;
            }
        }
    }
}

// ---------------- conv2 MFMA GEMM, LDS-free: 128x128 tile, K=384 ----------------
__global__ __launch_bounds__(256) void k_gemm2(
    const ushort* __restrict__ A, const ushort* __restrict__ WT,
    const float* __restrict__ inrm, const ushort* __restrict__ gid,
    const float* __restrict__ bias, float* __restrict__ out, int n)
{
    int tid  = threadIdx.x;
    int lane = tid & 63;
    int w    = tid >> 6;
    int wm   = w >> 1, wn = w & 1;
    int row0 = blockIdx.x * 128;
    int lr = lane & 15;
    int lk = lane >> 4;

    f32x4 acc[4][4];
    f32x4 zero = {0.f, 0.f, 0.f, 0.f};
    #pragma unroll
    for (int m = 0; m < 4; m++)
        #pragma unroll
        for (int nn = 0; nn < 4; nn++) acc[m][nn] = zero;

    int rg[4]; bool ok[4];
    #pragma unroll
    for (int m = 0; m < 4; m++) { rg[m] = row0 + wm * 64 + m * 16 + lr; ok[m] = rg[m] < n; }
    bf16x8 zf = {0, 0, 0, 0, 0, 0, 0, 0};

    #pragma unroll
    for (int ks = 0; ks < 12; ks++) {
        int koff = ks * 32 + lk * 8;
        bf16x8 af[4], bf[4];
        #pragma unroll
        for (int m = 0; m < 4; m++)
            af[m] = ok[m] ? *(const bf16x8*)&A[(size_t)rg[m] * 384 + koff] : zf;
        #pragma unroll
        for (int nn = 0; nn < 4; nn++) {
            int cg = wn * 64 + nn * 16 + lr;
            bf[nn] = *(const bf16x8*)&WT[(size_t)cg * 384 + koff];
        }
        #pragma unroll
        for (int m = 0; m < 4; m++)
            #pragma unroll
            for (int nn = 0; nn < 4; nn++)
                acc[m][nn] = __builtin_amdgcn_mfma_f32_16x16x32_bf16(af[m], bf[nn], acc[m][nn], 0, 0, 0);
    }

    #pragma unroll
    for (int m = 0; m < 4; m++) {
        int rb = row0 + wm * 64 + m * 16 + lk * 4;
        #pragma unroll
        for (int nn = 0; nn < 4; nn++) {
            int cg = wn * 64 + nn * 16 + lr;
            float bi = bias[cg];
            #pragma unroll
            for (int j = 0; j < 4; j++) {
                int r = rb + j;
                if (r >= n) continue;
                float ge = bf2f((uint)gid[(size_t)r * 128 + cg]);
                float t = acc[m][nn][j] * inrm[r] + bi + ge;
                out[(size_t)r * 384 + 256 + cg] = t;
            }
        }
    }
}

extern "C" void kernel_launch(void* const* d_in, const int* in_sizes, int n_in,
                              void* d_out, int out_size, void* d_ws, size_t ws_size,
                              hipStream_t stream) {
    const float* x      = (const float*)d_in[0];
    const float* id_emb = (const float*)d_in[1];
    const float* Wv0    = (const float*)d_in[2];
    const float* bv0    = (const float*)d_in[3];
    const float* Wv1    = (const float*)d_in[4];
    const float* bv1    = (const float*)d_in[5];
    const float* Wt0    = (const float*)d_in[6];
    const float* bt0    = (const float*)d_in[7];
    const float* Wt1    = (const float*)d_in[8];
    const float* bt1    = (const float*)d_in[9];
    const int*   src    = (const int*)d_in[10];
    const int*   dst    = (const int*)d_in[11];
    const int*   dsti   = (const int*)d_in[12];
    const int E = in_sizes[10];
    const int N = in_sizes[12];
    float* out = (float*)d_out;

    char* p = (char*)d_ws;
    ushort* xn_sc   = (ushort*)p; p += (size_t)N * 128 * 2;
    ushort* xhat_sc = (ushort*)p; p += (size_t)N * 256 * 2;
    ushort* z1      = (ushort*)p; p += (size_t)N * 128 * 2;
    ushort* zbig    = (ushort*)p; p += (size_t)N * 384 * 2;
    ushort* gid     = (ushort*)p; p += (size_t)N * 128 * 2;
    ushort* W1T     = (ushort*)p; p += 256 * 128 * 2;
    ushort* W2T     = (ushort*)p; p += 128 * 384 * 2;
    float* bias_cat = (float*)p;  p += 256 * 4;
    float* bias2    = (float*)p;  p += 128 * 4;
    float* onrm     = (float*)p;  p += (size_t)N * 4;
    float* inrm     = (float*)p;  p += (size_t)N * 4;
    int* deg_out    = (int*)p;    p += (size_t)N * 4;
    int* deg_in     = (int*)p;    p += (size_t)N * 4;
    int* cursor     = (int*)p;    p += (size_t)N * 4;
    int* row_ptr    = (int*)p;    p += (size_t)(N + 1) * 4;
    int* csum       = (int*)p;    p += 1024 * 4;
    int* col        = (int*)p;    p += (size_t)E * 4;

    hipMemsetAsync(deg_out, 0, (size_t)N * 3 * 4, stream);   // deg_out|deg_in|cursor contiguous

    int be = (E + 255) / 256;
    int bn = (N + 255) / 256;
    int bw = (N * 64 + 255) / 256;          // one wave per row
    int bg = (N + 127) / 128;               // 128-row GEMM tiles
    int nb = (N + 1023) / 1024;             // scan chunks

    k_degrees<<<be, 256, 0, stream>>>(src, dst, deg_out, deg_in, E);
    k_norms  <<<bn, 256, 0, stream>>>(deg_out, deg_in, onrm, inrm, N);
    k_scan1  <<<nb, 1024, 0, stream>>>(deg_in, row_ptr, csum, N);
    k_scan2  <<<1, 1024, 0, stream>>>(csum, nb);
    k_scan3  <<<bn, 256, 0, stream>>>(row_ptr, csum, N);
    k_fill   <<<be, 256, 0, stream>>>(src, dst, row_ptr, cursor, col, E);
    k_wprep  <<<192, 256, 0, stream>>>(Wv0, Wt0, Wv1, Wt1, bv0, bt0, bv1, bt1,
                                       W1T, W2T, bias_cat, bias2);
    k_normx  <<<bw, 256, 0, stream>>>(x, onrm, dsti, id_emb, xn_sc, gid, out, N);

    k_agg1 <<<bw, 256, 0, stream>>>(xn_sc, row_ptr, col, z1, zbig, N);
    k_gemm1<<<bg, 256, 0, stream>>>(z1, W1T, inrm, onrm, gid, bias_cat, xhat_sc, out, N);
    k_agg2 <<<bw, 256, 0, stream>>>(xhat_sc, row_ptr, col, zbig, N);
    k_gemm2<<<bg, 256, 0, stream>>>(zbig, W2T, inrm, gid, bias2, out, N);
}